// Round 16
// baseline (724.946 us; speedup 1.0000x reference)
//
#include <hip/hip_runtime.h>
#include <hip/hip_bf16.h>

#define S_LEN 2048
#define DMODEL 4096
#define NH 32
#define NKV 8
#define HD 128
#define NQKV 6144
#define VOFF (DMODEL + NKV * HD)  // v-section offset inside a qkv row
// 1/sqrt(128) * log2(e): scores in log2 domain so v_exp_f32 (=2^x) is the exp
#define ATT_SCALE_L2E 0.1275175213528852f

typedef __bf16 bf16x8 __attribute__((ext_vector_type(8)));
typedef __bf16 bf16x4 __attribute__((ext_vector_type(4)));
typedef float f32x4 __attribute__((ext_vector_type(4)));

template <bool B> struct BoolC { static constexpr bool value = B; };

// float -> bf16 bits, round-to-nearest-even
__device__ __forceinline__ unsigned short f2b(float f) {
  union { float f; unsigned u; } a; a.f = f;
  unsigned u = a.u;
  return (unsigned short)((u + 0x7FFFu + ((u >> 16) & 1u)) >> 16);
}
// bf16 bits -> float
__device__ __forceinline__ float b2f(unsigned short u) {
  union { unsigned u; float f; } a; a.u = (unsigned)u << 16; return a.f;
}

__device__ __forceinline__ void gl16(const unsigned short* g, unsigned short* l) {
  __builtin_amdgcn_global_load_lds(
      (const __attribute__((address_space(1))) unsigned int*)g,
      (__attribute__((address_space(3))) unsigned int*)l, 16, 0, 0);
}

// ============ merged prep: x fp32->bf16 + 4 weight transposes (one launch) ============
__global__ __launch_bounds__(256) void k_prep(const float* __restrict__ x,
                                              const float* __restrict__ Wq,
                                              const float* __restrict__ Wk,
                                              const float* __restrict__ Wv,
                                              const float* __restrict__ Wo,
                                              unsigned short* __restrict__ xb,
                                              unsigned short* __restrict__ wqkv_t,
                                              unsigned short* __restrict__ wo_t) {
  __shared__ float tile[64][65];
  const int id = blockIdx.x;
  if (id >= 10240) {  // ---- cvt_x ----
    int i = (id - 10240) * 256 + threadIdx.x;
    float4 v = ((const float4*)x)[i];
    ushort4 o;
    o.x = f2b(v.x); o.y = f2b(v.y); o.z = f2b(v.z); o.w = f2b(v.w);
    ((ushort4*)xb)[i] = o;
    return;
  }
  const float* W;
  unsigned short* Wt;
  int N, bx, by;
  if (id < 4096)      { W = Wq; Wt = wqkv_t;                         N = 4096; bx = id & 63;          by = id >> 6; }
  else if (id < 5120) { W = Wk; Wt = wqkv_t + (size_t)4096 * 4096;   N = 1024; bx = (id - 4096) & 63; by = (id - 4096) >> 6; }
  else if (id < 6144) { W = Wv; Wt = wqkv_t + (size_t)5120 * 4096;   N = 1024; bx = (id - 5120) & 63; by = (id - 5120) >> 6; }
  else                { W = Wo; Wt = wo_t;                           N = 4096; bx = (id - 6144) & 63; by = (id - 6144) >> 6; }
  const int k0 = bx * 64, n0 = by * 64;
  const int tx = threadIdx.x & 31, ty = threadIdx.x >> 5;
#pragma unroll
  for (int i = 0; i < 8; ++i) {
    int k = ty + i * 8;
    const float* src = W + (size_t)(k0 + k) * N + n0;
    tile[k][tx] = src[tx];
    tile[k][tx + 32] = src[tx + 32];
  }
  __syncthreads();
  int kq = threadIdx.x & 15, nb = threadIdx.x >> 4;
#pragma unroll
  for (int i = 0; i < 4; ++i) {
    int n = nb + i * 16;
    ushort4 o;
    o.x = f2b(tile[kq * 4 + 0][n]);
    o.y = f2b(tile[kq * 4 + 1][n]);
    o.z = f2b(tile[kq * 4 + 2][n]);
    o.w = f2b(tile[kq * 4 + 3][n]);
    *(ushort4*)&Wt[(size_t)(n0 + n) * 4096 + k0 + kq * 4] = o;
  }
}

// ============ merged post-proj: RoPE+int8 quant (q,k) + V^T transpose ============
__global__ __launch_bounds__(256) void k_post(const unsigned short* __restrict__ qkv,
                                              const float* __restrict__ cost,
                                              const float* __restrict__ sint,
                                              unsigned short* __restrict__ q_int,
                                              float* __restrict__ q_ds_t,
                                              unsigned short* __restrict__ k_int,
                                              float* __restrict__ k_ds_t,
                                              unsigned short* __restrict__ v_t) {
  __shared__ unsigned short tile[64][65];
  const int id = blockIdx.x;
  if (id < 20480) {
    int y = id >> 11, s = id & 2047;
    int wv = threadIdx.x >> 6, l = threadIdx.x & 63;
    int hh = y * 4 + wv;
    const unsigned short* row = qkv + (size_t)s * NQKV;
    int off = (hh < NH) ? hh * HD : DMODEL + (hh - NH) * HD;
    float t1 = b2f(row[off + l]), t2 = b2f(row[off + 64 + l]);
    float c1 = cost[s * HD + l],      sn1 = sint[s * HD + l];
    float c2 = cost[s * HD + 64 + l], sn2 = sint[s * HD + 64 + l];
    float o1 = t1 * c1 - t2 * sn1;
    float o2 = t2 * c2 + t1 * sn2;
    float amax = fmaxf(fabsf(o1), fabsf(o2));
#pragma unroll
    for (int m = 1; m < 64; m <<= 1) amax = fmaxf(amax, __shfl_xor(amax, m));
    amax = fmaxf(amax, 1e-5f);
    float scale = 127.0f / amax;
    float dscale = amax * (1.0f / 127.0f);
    float v1 = fminf(fmaxf(rintf(o1 * scale), -128.f), 127.f);
    float v2 = fminf(fmaxf(rintf(o2 * scale), -128.f), 127.f);
    if (hh < NH) {
      unsigned short* dst = q_int + ((size_t)s * NH + hh) * HD;
      dst[l] = f2b(v1); dst[l + 64] = f2b(v2);
      if (l == 0) q_ds_t[(size_t)hh * S_LEN + s] = dscale;
    } else {
      int kh = hh - NH;
      unsigned short* dst = k_int + ((size_t)s * NKV + kh) * HD;
      dst[l] = f2b(v1); dst[l + 64] = f2b(v2);
      if (l == 0) k_ds_t[(size_t)kh * S_LEN + s] = dscale;
    }
    return;
  }
  int vid = id - 20480;
  int s0 = (vid & 31) * 64, d0 = ((vid >> 5) & 1) * 64, kvh = vid >> 6;
  int tx = threadIdx.x & 63, ty = threadIdx.x >> 6;
#pragma unroll
  for (int i = 0; i < 16; ++i) {
    int s = ty + i * 4;
    tile[s][tx] = qkv[(size_t)(s0 + s) * NQKV + VOFF + kvh * HD + d0 + tx];
  }
  __syncthreads();
#pragma unroll
  for (int i = 0; i < 16; ++i) {
    int d = ty + i * 4;
    v_t[((size_t)kvh * HD + d0 + d) * S_LEN + s0 + tx] = tile[tx][d];
  }
}

// ===== 128 x 192 GEMM, K-SPLIT waves (2M x 2N x 2K), per-wave 64x96 — QKV proj =====
// 8 waves: wm=wvid&1, wn=(wvid>>1)&1, wk=wvid>>2. Each wave owns ks-half wk of a 64x96
// output tile: 4 A + 6 B reads -> 24 MFMA per K-tile (reads/MFMA 0.417 vs 0.583 before;
// block LDS-read floor 2690 -> 1920 cyc/K-tile). LDS 80 KB -> 2 blocks/CU. Epilogue:
// two 48KB LDS exchange rounds merge the ks-halves (fp32 exact). acc 96 VGPR + ~10
// transient fits the 128 cap (FN=3 measured 52 for 48 acc -> operands are transient).
__global__ __launch_bounds__(512, 4) void k_g192ks(const unsigned short* __restrict__ A,
                                                   const unsigned short* __restrict__ B,
                                                   unsigned short* __restrict__ C,
                                                   int M, int N, int K) {
  extern __shared__ __align__(16) unsigned short smem[];
  char* Sc = (char*)smem;
  const int tid = threadIdx.x;
  const int wvid = tid >> 6, l = tid & 63;
  const int wm = wvid & 1, wn = (wvid >> 1) & 1, wk = wvid >> 2;
  const int l15 = l & 15, l4 = l >> 4;

  const int cpx = gridDim.x >> 3;
  const int swz = (blockIdx.x & 7) * cpx + (blockIdx.x >> 3);
  const int mtiles = M >> 7;
  const int m0 = (swz % mtiles) * 128;
  const int n0 = (swz / mtiles) * 192;

  const int NT = K >> 6;

  const int rsw = (l15 & 7) << 4;
  const int a_base = (wm * 64 + l15) * 128;        // + fm*2048 + ck
  const int b_base = (wn * 96 + l15) * 128;        // + fn*2048 + ck
  const int ck = (wk * 64 + l4 * 16) ^ rsw;        // this wave's ks-half column

  const int srow = l >> 3;
  const int st_k8 = (l & 7) ^ (srow & 7);

  auto stA = [&](int tt) {  // 16 KB: 2 gl16/thread
    if (tt >= NT) return;
    const unsigned short* g = A + (size_t)(m0 + wvid * 8 + srow) * K + tt * 64 + st_k8 * 8;
    char* lb = Sc + (tt & 1) * 16384 + wvid * 1024;
#pragma unroll
    for (int j = 0; j < 2; ++j)
      gl16(g + (size_t)(j * 64) * K, (unsigned short*)(lb + j * 8192));
  };
  auto stB = [&](int tt) {  // 24 KB: 3 gl16/thread
    if (tt >= NT) return;
    const unsigned short* g = B + (size_t)(n0 + wvid * 8 + srow) * K + tt * 64 + st_k8 * 8;
    char* lb = Sc + 32768 + (tt & 1) * 24576 + wvid * 1024;
#pragma unroll
    for (int j = 0; j < 3; ++j)
      gl16(g + (size_t)(j * 64) * K, (unsigned short*)(lb + j * 8192));
  };

  f32x4 acc[4][6] = {};

  stA(0); stB(0); stA(1);
  if (NT > 1) asm volatile("s_waitcnt vmcnt(2)" ::: "memory");
  else        asm volatile("s_waitcnt vmcnt(0)" ::: "memory");
  __builtin_amdgcn_s_barrier();

  for (int t = 0; t < NT; ++t) {
    const char* Ab = Sc + (t & 1) * 16384;
    const char* Bb = Sc + 32768 + (t & 1) * 24576;
    stB(t + 1);
    bf16x8 a[4], b[6];
#pragma unroll
    for (int fm = 0; fm < 4; ++fm) a[fm] = *(const bf16x8*)(Ab + a_base + fm * 2048 + ck);
#pragma unroll
    for (int fn = 0; fn < 6; ++fn) b[fn] = *(const bf16x8*)(Bb + b_base + fn * 2048 + ck);
    __builtin_amdgcn_s_setprio(1);
#pragma unroll
    for (int fm = 0; fm < 4; ++fm)
#pragma unroll
      for (int fn = 0; fn < 6; ++fn)
        acc[fm][fn] = __builtin_amdgcn_mfma_f32_16x16x32_bf16(a[fm], b[fn], acc[fm][fn], 0, 0, 0);
    __builtin_amdgcn_s_setprio(0);
    __builtin_amdgcn_s_barrier();
    stA(t + 2);
    if (t + 1 < NT) {
      if (t + 1 == NT - 1) asm volatile("s_waitcnt vmcnt(0)" ::: "memory");
      else                 asm volatile("s_waitcnt vmcnt(2)" ::: "memory");
      __builtin_amdgcn_s_barrier();
    }
  }

  // ---- epilogue: merge ks-halves via LDS in two 48KB rounds (LDS dead; staging drained
  // by the vmcnt(0) at t=NT-2's boundary) ----
  const int pairid = wm * 2 + wn;
  char* xch = Sc + pairid * 12288;
#pragma unroll
  for (int h = 0; h < 2; ++h) {
    if (wk == 1) {
#pragma unroll
      for (int fm2 = 0; fm2 < 2; ++fm2)
#pragma unroll
        for (int fn = 0; fn < 6; ++fn)
          *(f32x4*)(xch + (fm2 * 6 + fn) * 1024 + l * 16) = acc[h * 2 + fm2][fn];
    }
    __syncthreads();
    if (wk == 0) {
#pragma unroll
      for (int fm2 = 0; fm2 < 2; ++fm2) {
        int fm = h * 2 + fm2;
        int row0 = m0 + wm * 64 + fm * 16 + l4 * 4;
#pragma unroll
        for (int fn = 0; fn < 6; ++fn) {
          f32x4 o = *(const f32x4*)(xch + (fm2 * 6 + fn) * 1024 + l * 16);
          int col = n0 + wn * 96 + fn * 16 + l15;
#pragma unroll
          for (int r = 0; r < 4; ++r)
            C[(size_t)(row0 + r) * N + col] = f2b(acc[fm][fn][r] + o[r]);
        }
      }
    }
    __syncthreads();
  }
}

// ===== 128 x 128 GEMM, K-SPLIT waves, per-wave 64x64 — out proj (round-15 proven) =====
__global__ __launch_bounds__(512, 4) void k_gksplit(const unsigned short* __restrict__ A,
                                                    const unsigned short* __restrict__ B,
                                                    float* __restrict__ C,
                                                    int M, int N, int K) {
  extern __shared__ __align__(16) unsigned short smem[];
  char* Sc = (char*)smem;
  const int tid = threadIdx.x;
  const int wvid = tid >> 6, l = tid & 63;
  const int wm = wvid & 1, wn = (wvid >> 1) & 1, wk = wvid >> 2;
  const int l15 = l & 15, l4 = l >> 4;

  const int cpx = gridDim.x >> 3;
  const int swz = (blockIdx.x & 7) * cpx + (blockIdx.x >> 3);
  const int mtiles = M >> 7;
  const int m0 = (swz % mtiles) * 128;
  const int n0 = (swz / mtiles) * 128;

  const int NT = K >> 6;

  const int rsw = (l15 & 7) << 4;
  const int a_base = (wm * 64 + l15) * 128;
  const int b_base = (wn * 64 + l15) * 128;
  const int ck = (wk * 64 + l4 * 16) ^ rsw;

  const int srow = l >> 3;
  const int st_k8 = (l & 7) ^ (srow & 7);

  auto stA = [&](int tt) {
    if (tt >= NT) return;
    const unsigned short* g = A + (size_t)(m0 + wvid * 8 + srow) * K + tt * 64 + st_k8 * 8;
    char* lb = Sc + (tt & 1) * 16384 + wvid * 1024;
#pragma unroll
    for (int j = 0; j < 2; ++j)
      gl16(g + (size_t)(j * 64) * K, (unsigned short*)(lb + j * 8192));
  };
  auto stB = [&](int tt) {
    if (tt >= NT) return;
    const unsigned short* g = B + (size_t)(n0 + wvid * 8 + srow) * K + tt * 64 + st_k8 * 8;
    char* lb = Sc + 32768 + (tt & 1) * 16384 + wvid * 1024;
#pragma unroll
    for (int j = 0; j < 2; ++j)
      gl16(g + (size_t)(j * 64) * K, (unsigned short*)(lb + j * 8192));
  };

  f32x4 acc[4][4] = {};

  stA(0); stB(0); stA(1);
  if (NT > 1) asm volatile("s_waitcnt vmcnt(2)" ::: "memory");
  else        asm volatile("s_waitcnt vmcnt(0)" ::: "memory");
  __builtin_amdgcn_s_barrier();

  for (int t = 0; t < NT; ++t) {
    const char* Ab = Sc + (t & 1) * 16384;
    const char* Bb = Sc + 32768 + (t & 1) * 16384;
    stB(t + 1);
    bf16x8 a[4], b[4];
#pragma unroll
    for (int fm = 0; fm < 4; ++fm) a[fm] = *(const bf16x8*)(Ab + a_base + fm * 2048 + ck);
#pragma unroll
    for (int fn = 0; fn < 4; ++fn) b[fn] = *(const bf16x8*)(Bb + b_base + fn * 2048 + ck);
    __builtin_amdgcn_s_setprio(1);
#pragma unroll
    for (int fm = 0; fm < 4; ++fm)
#pragma unroll
      for (int fn = 0; fn < 4; ++fn)
        acc[fm][fn] = __builtin_amdgcn_mfma_f32_16x16x32_bf16(a[fm], b[fn], acc[fm][fn], 0, 0, 0);
    __builtin_amdgcn_s_setprio(0);
    __builtin_amdgcn_s_barrier();
    stA(t + 2);
    if (t + 1 < NT) {
      if (t + 1 == NT - 1) asm volatile("s_waitcnt vmcnt(0)" ::: "memory");
      else                 asm volatile("s_waitcnt vmcnt(2)" ::: "memory");
      __builtin_amdgcn_s_barrier();
    }
  }

  char* xch = Sc + (wm * 2 + wn) * 16384;
  if (wk == 1) {
#pragma unroll
    for (int fm = 0; fm < 4; ++fm)
#pragma unroll
      for (int fn = 0; fn < 4; ++fn)
        *(f32x4*)(xch + (fm * 4 + fn) * 1024 + l * 16) = acc[fm][fn];
  }
  __syncthreads();
  if (wk == 0) {
#pragma unroll
    for (int fm = 0; fm < 4; ++fm) {
      int row0 = m0 + wm * 64 + fm * 16 + l4 * 4;
#pragma unroll
      for (int fn = 0; fn < 4; ++fn) {
        f32x4 o = *(const f32x4*)(xch + (fm * 4 + fn) * 1024 + l * 16);
        int col = n0 + wn * 64 + fn * 16 + l15;
#pragma unroll
        for (int r = 0; r < 4; ++r)
          C[(size_t)(row0 + r) * N + col] = acc[fm][fn][r] + o[r];
      }
    }
  }
}

// ------------- causal GQA flash attention (round-14 proven) -------------
__global__ __launch_bounds__(512, 4) void k_attn(const unsigned short* __restrict__ q_int,
                                                 const float* __restrict__ q_ds_t,
                                                 const unsigned short* __restrict__ k_int,
                                                 const float* __restrict__ k_ds_t,
                                                 const unsigned short* __restrict__ v_t,
                                                 unsigned short* __restrict__ o_bf) {
  __shared__ __align__(16) unsigned short K_lds[2][8192];
  __shared__ __align__(16) unsigned short V_lds[2][8192];
  __shared__ __align__(16) unsigned short P_lds[8][1024];

  const int bid = blockIdx.x;
  const int kvh = bid & 7;
  const int qt = 63 - (bid >> 3);
  const int tid = threadIdx.x, wv = tid >> 6, l = tid & 63;
  const int l15 = l & 15, l4 = l >> 4;
  const int h = kvh * 4 + (wv & 3);
  const int rh = wv >> 2;

  auto stage = [&](int b, int kt) {
    const unsigned short* kB = k_int + (size_t)kt * 64 * (NKV * HD) + kvh * HD;
    const unsigned short* vB = v_t + (size_t)kvh * HD * S_LEN + (size_t)kt * 64;
#pragma unroll
    for (int j = 0; j < 2; ++j) {
      int wi = j * 8 + wv;
      int slot = wi * 64 + l;
      int key = slot >> 4;
      int colb = ((slot & 15) * 16) ^ ((key & 7) << 4);
      gl16(kB + key * (NKV * HD) + (colb >> 1), &K_lds[b][wi * 512]);
      int d = slot >> 3;
      int ckb = ((slot & 7) * 16) ^ ((d & 7) << 4);
      gl16(vB + (size_t)d * S_LEN + (ckb >> 1), &V_lds[b][wi * 512]);
    }
  };

  const int qrow_lo = qt * 32 + rh * 16;
  const int qg = qrow_lo + l15;
  const int crow = qrow_lo + l4 * 4;

  bf16x8 qf[4];
  {
    const unsigned short* qp = q_int + ((size_t)qg * NH + h) * HD + l4 * 8;
#pragma unroll
    for (int kd = 0; kd < 4; ++kd) qf[kd] = *(const bf16x8*)(qp + kd * 32);
  }
  const float qsS = ATT_SCALE_L2E * q_ds_t[(size_t)h * S_LEN + qg];

  float m_run = -3.0e38f, l_run = 0.f;
  f32x4 o_acc[8] = {};

  const int nkt = (qt >> 1) + 1;
  stage(0, 0);
  __syncthreads();

  const int psw = (l15 & 7) << 4;

  auto tileBody = [&](auto mc, int kt) {
    constexpr bool MASKED = decltype(mc)::value;
    const int cur = kt & 1;
    f32x4 ksd[4];
    {
      const f32x4* kdp = (const f32x4*)(k_ds_t + (size_t)kvh * S_LEN + kt * 64 + l4 * 4);
#pragma unroll
      for (int nt = 0; nt < 4; ++nt) ksd[nt] = kdp[nt * 4];
    }
    if (kt + 1 < nkt) stage(cur ^ 1, kt + 1);

    f32x4 sacc[4] = {};
#pragma unroll
    for (int nt = 0; nt < 4; ++nt) {
      int key = nt * 16 + l15;
#pragma unroll
      for (int kd = 0; kd < 4; ++kd) {
        int byte = key * 256 + kd * 64 + l4 * 16;
        byte ^= (key & 7) << 4;
        bf16x8 kf = *(const bf16x8*)((const char*)&K_lds[cur][0] + byte);
        sacc[nt] = __builtin_amdgcn_mfma_f32_16x16x32_bf16(kf, qf[kd], sacc[nt], 0, 0, 0);
      }
    }

    float p[4][4];
    float tmax = -3.0e38f;
#pragma unroll
    for (int nt = 0; nt < 4; ++nt) {
#pragma unroll
      for (int r = 0; r < 4; ++r) {
        float sc = sacc[nt][r] * (qsS * ksd[nt][r]);
        if constexpr (MASKED) {
          int keyg = kt * 64 + nt * 16 + l4 * 4 + r;
          sc = (keyg <= qg) ? sc : -3.0e38f;
        }
        p[nt][r] = sc;
        tmax = fmaxf(tmax, sc);
      }
    }
    tmax = fmaxf(tmax, __shfl_xor(tmax, 16));
    tmax = fmaxf(tmax, __shfl_xor(tmax, 32));

    float nm = fmaxf(m_run, tmax);
    bool need = tmax > m_run + 11.0f;
    if (__ballot(need)) {
      float corr = __builtin_amdgcn_exp2f(m_run - nm);
      m_run = nm;
      l_run *= corr;
      float cq[4];
#pragma unroll
      for (int r = 0; r < 4; ++r) cq[r] = __shfl(corr, (l & 48) | (l4 * 4 + r));
#pragma unroll
      for (int dt = 0; dt < 8; ++dt)
#pragma unroll
        for (int r = 0; r < 4; ++r) o_acc[dt][r] *= cq[r];
    }

    float psum = 0.f;
#pragma unroll
    for (int nt = 0; nt < 4; ++nt)
#pragma unroll
      for (int r = 0; r < 4; ++r) {
        float e = __builtin_amdgcn_exp2f(p[nt][r] - m_run);
        p[nt][r] = e;
        psum += e;
      }
    psum += __shfl_xor(psum, 16);
    psum += __shfl_xor(psum, 32);
    l_run += psum;

#pragma unroll
    for (int nt = 0; nt < 4; ++nt) {
      bf16x4 pk;
      pk[0] = (__bf16)p[nt][0]; pk[1] = (__bf16)p[nt][1];
      pk[2] = (__bf16)p[nt][2]; pk[3] = (__bf16)p[nt][3];
      int bw = l15 * 128 + ((nt * 32 + l4 * 8) ^ psw);
      *(bf16x4*)((char*)&P_lds[wv][0] + bw) = pk;
    }
    bf16x8 pa[2];
#pragma unroll
    for (int kc = 0; kc < 2; ++kc) {
      int br = l15 * 128 + ((kc * 64 + l4 * 16) ^ psw);
      pa[kc] = *(const bf16x8*)((const char*)&P_lds[wv][0] + br);
    }

#pragma unroll
    for (int dt = 0; dt < 8; ++dt) {
      int d = dt * 16 + l15;
      int swzv = (d & 7) << 4;
#pragma unroll
      for (int kc = 0; kc < 2; ++kc) {
        int byte = d * 128 + ((kc * 64 + l4 * 16) ^ swzv);
        bf16x8 vb = *(const bf16x8*)((const char*)&V_lds[cur][0] + byte);
        o_acc[dt] = __builtin_amdgcn_mfma_f32_16x16x32_bf16(pa[kc], vb, o_acc[dt], 0, 0, 0);
      }
    }
    __syncthreads();
  };

  for (int kt = 0; kt + 1 < nkt; ++kt) tileBody(BoolC<false>{}, kt);
  tileBody(BoolC<true>{}, nkt - 1);

  float inv = 1.0f / l_run;
  float invq[4];
#pragma unroll
  for (int r = 0; r < 4; ++r) invq[r] = __shfl(inv, (l & 48) | (l4 * 4 + r));
#pragma unroll
  for (int dt = 0; dt < 8; ++dt)
#pragma unroll
    for (int r = 0; r < 4; ++r)
      o_bf[(size_t)(crow + r) * (NH * HD) + h * HD + dt * 16 + l15] =
          f2b(o_acc[dt][r] * invq[r]);
}

extern "C" void kernel_launch(void* const* d_in, const int* in_sizes, int n_in,
                              void* d_out, int out_size, void* d_ws, size_t ws_size,
                              hipStream_t stream) {
  const float* x    = (const float*)d_in[0];
  const float* Wq   = (const float*)d_in[1];
  const float* Wk   = (const float*)d_in[2];
  const float* Wv   = (const float*)d_in[3];
  const float* Wo   = (const float*)d_in[4];
  const float* cost = (const float*)d_in[5];
  const float* sint = (const float*)d_in[6];
  float* out = (float*)d_out;
  char* ws = (char*)d_ws;

  unsigned short* xb     = (unsigned short*)(ws);                 // 16 MB (dead after gemm1)
  unsigned short* wqkv_t = (unsigned short*)(ws + 16777216);      // 48 MB (dead after gemm1)
  unsigned short* wo_t   = (unsigned short*)(ws + 67108864);      // 32 MB (4096x4096)
  unsigned short* qkv    = (unsigned short*)(ws + 100663296);     // 24 MB bf16
  unsigned short* q_int  = (unsigned short*)(ws + 150994944);     // 16 MB
  unsigned short* k_int  = (unsigned short*)(ws + 167772160);     // 4 MB
  float*          q_ds_t = (float*)(ws + 176160768);              // 256 KB [NH][S]
  float*          k_ds_t = (float*)(ws + 176422912);              // 64 KB  [NKV][S]
  unsigned short* o_bf   = (unsigned short*)(ws + 176488448);     // 16 MB
  unsigned short* v_t    = (unsigned short*)(ws);                 // 4 MB, aliases dead xb

  hipFuncSetAttribute((const void*)k_g192ks,
                      hipFuncAttributeMaxDynamicSharedMemorySize, 81920);
  hipFuncSetAttribute((const void*)k_gksplit,
                      hipFuncAttributeMaxDynamicSharedMemorySize, 65536);

  // merged prep: cvt_x + Wq/Wk/Wv/Wo transposes in one launch
  k_prep<<<dim3(18432), 256, 0, stream>>>(x, Wq, Wk, Wv, Wo, xb, wqkv_t, wo_t);
  // QKV proj: 128x192 tiles, K-split waves (per-wave 64x96) -> 512 blocks = 2/CU; bf16 out
  k_g192ks<<<dim3(512), 512, 81920, stream>>>(xb, wqkv_t, qkv, 2048, 6144, 4096);
  // merged post: RoPE+quant (q,k) + V^T transpose in one launch
  k_post<<<dim3(20992), 256, 0, stream>>>(qkv, cost, sint, q_int, q_ds_t, k_int, k_ds_t, v_t);
  // attention: 512 blocks x 512 threads (4 heads x 32 q-rows each), mask-elided tiles
  k_attn<<<dim3(512), 512, 0, stream>>>(q_int, q_ds_t, k_int, k_ds_t, v_t, o_bf);
  // out proj: 128x128 tiles, K-split waves (per-wave 64x64) -> 512 blocks = 2/CU
  k_gksplit<<<dim3(512), 512, 65536, stream>>>(o_bf, wo_t, out, 2048, 4096, 4096);
}

// Round 17
// 306.731 us; speedup vs baseline: 2.3635x; 2.3635x over previous
//
#include <hip/hip_runtime.h>
#include <hip/hip_bf16.h>

#define S_LEN 2048
#define DMODEL 4096
#define NH 32
#define NKV 8
#define HD 128
#define NQKV 6144
#define VOFF (DMODEL + NKV * HD)  // v-section offset inside a qkv row
// 1/sqrt(128) * log2(e): scores in log2 domain so v_exp_f32 (=2^x) is the exp
#define ATT_SCALE_L2E 0.1275175213528852f

typedef __bf16 bf16x8 __attribute__((ext_vector_type(8)));
typedef __bf16 bf16x4 __attribute__((ext_vector_type(4)));
typedef float f32x4 __attribute__((ext_vector_type(4)));

template <bool B> struct BoolC { static constexpr bool value = B; };

// float -> bf16 bits, round-to-nearest-even
__device__ __forceinline__ unsigned short f2b(float f) {
  union { float f; unsigned u; } a; a.f = f;
  unsigned u = a.u;
  return (unsigned short)((u + 0x7FFFu + ((u >> 16) & 1u)) >> 16);
}
// bf16 bits -> float
__device__ __forceinline__ float b2f(unsigned short u) {
  union { unsigned u; float f; } a; a.u = (unsigned)u << 16; return a.f;
}

__device__ __forceinline__ void gl16(const unsigned short* g, unsigned short* l) {
  __builtin_amdgcn_global_load_lds(
      (const __attribute__((address_space(1))) unsigned int*)g,
      (__attribute__((address_space(3))) unsigned int*)l, 16, 0, 0);
}

// ============ merged prep: x fp32->bf16 + 4 weight transposes (one launch) ============
__global__ __launch_bounds__(256) void k_prep(const float* __restrict__ x,
                                              const float* __restrict__ Wq,
                                              const float* __restrict__ Wk,
                                              const float* __restrict__ Wv,
                                              const float* __restrict__ Wo,
                                              unsigned short* __restrict__ xb,
                                              unsigned short* __restrict__ wqkv_t,
                                              unsigned short* __restrict__ wo_t) {
  __shared__ float tile[64][65];
  const int id = blockIdx.x;
  if (id >= 10240) {  // ---- cvt_x ----
    int i = (id - 10240) * 256 + threadIdx.x;
    float4 v = ((const float4*)x)[i];
    ushort4 o;
    o.x = f2b(v.x); o.y = f2b(v.y); o.z = f2b(v.z); o.w = f2b(v.w);
    ((ushort4*)xb)[i] = o;
    return;
  }
  const float* W;
  unsigned short* Wt;
  int N, bx, by;
  if (id < 4096)      { W = Wq; Wt = wqkv_t;                         N = 4096; bx = id & 63;          by = id >> 6; }
  else if (id < 5120) { W = Wk; Wt = wqkv_t + (size_t)4096 * 4096;   N = 1024; bx = (id - 4096) & 63; by = (id - 4096) >> 6; }
  else if (id < 6144) { W = Wv; Wt = wqkv_t + (size_t)5120 * 4096;   N = 1024; bx = (id - 5120) & 63; by = (id - 5120) >> 6; }
  else                { W = Wo; Wt = wo_t;                           N = 4096; bx = (id - 6144) & 63; by = (id - 6144) >> 6; }
  const int k0 = bx * 64, n0 = by * 64;
  const int tx = threadIdx.x & 31, ty = threadIdx.x >> 5;
#pragma unroll
  for (int i = 0; i < 8; ++i) {
    int k = ty + i * 8;
    const float* src = W + (size_t)(k0 + k) * N + n0;
    tile[k][tx] = src[tx];
    tile[k][tx + 32] = src[tx + 32];
  }
  __syncthreads();
  int kq = threadIdx.x & 15, nb = threadIdx.x >> 4;
#pragma unroll
  for (int i = 0; i < 4; ++i) {
    int n = nb + i * 16;
    ushort4 o;
    o.x = f2b(tile[kq * 4 + 0][n]);
    o.y = f2b(tile[kq * 4 + 1][n]);
    o.z = f2b(tile[kq * 4 + 2][n]);
    o.w = f2b(tile[kq * 4 + 3][n]);
    *(ushort4*)&Wt[(size_t)(n0 + n) * 4096 + k0 + kq * 4] = o;
  }
}

// ============ merged post-proj: RoPE+int8 quant (q,k) + V^T transpose ============
__global__ __launch_bounds__(256) void k_post(const unsigned short* __restrict__ qkv,
                                              const float* __restrict__ cost,
                                              const float* __restrict__ sint,
                                              unsigned short* __restrict__ q_int,
                                              float* __restrict__ q_ds_t,
                                              unsigned short* __restrict__ k_int,
                                              float* __restrict__ k_ds_t,
                                              unsigned short* __restrict__ v_t) {
  __shared__ unsigned short tile[64][65];
  const int id = blockIdx.x;
  if (id < 20480) {
    int y = id >> 11, s = id & 2047;
    int wv = threadIdx.x >> 6, l = threadIdx.x & 63;
    int hh = y * 4 + wv;
    const unsigned short* row = qkv + (size_t)s * NQKV;
    int off = (hh < NH) ? hh * HD : DMODEL + (hh - NH) * HD;
    float t1 = b2f(row[off + l]), t2 = b2f(row[off + 64 + l]);
    float c1 = cost[s * HD + l],      sn1 = sint[s * HD + l];
    float c2 = cost[s * HD + 64 + l], sn2 = sint[s * HD + 64 + l];
    float o1 = t1 * c1 - t2 * sn1;
    float o2 = t2 * c2 + t1 * sn2;
    float amax = fmaxf(fabsf(o1), fabsf(o2));
#pragma unroll
    for (int m = 1; m < 64; m <<= 1) amax = fmaxf(amax, __shfl_xor(amax, m));
    amax = fmaxf(amax, 1e-5f);
    float scale = 127.0f / amax;
    float dscale = amax * (1.0f / 127.0f);
    float v1 = fminf(fmaxf(rintf(o1 * scale), -128.f), 127.f);
    float v2 = fminf(fmaxf(rintf(o2 * scale), -128.f), 127.f);
    if (hh < NH) {
      unsigned short* dst = q_int + ((size_t)s * NH + hh) * HD;
      dst[l] = f2b(v1); dst[l + 64] = f2b(v2);
      if (l == 0) q_ds_t[(size_t)hh * S_LEN + s] = dscale;
    } else {
      int kh = hh - NH;
      unsigned short* dst = k_int + ((size_t)s * NKV + kh) * HD;
      dst[l] = f2b(v1); dst[l + 64] = f2b(v2);
      if (l == 0) k_ds_t[(size_t)kh * S_LEN + s] = dscale;
    }
    return;
  }
  int vid = id - 20480;
  int s0 = (vid & 31) * 64, d0 = ((vid >> 5) & 1) * 64, kvh = vid >> 6;
  int tx = threadIdx.x & 63, ty = threadIdx.x >> 6;
#pragma unroll
  for (int i = 0; i < 16; ++i) {
    int s = ty + i * 4;
    tile[s][tx] = qkv[(size_t)(s0 + s) * NQKV + VOFF + kvh * HD + d0 + tx];
  }
  __syncthreads();
#pragma unroll
  for (int i = 0; i < 16; ++i) {
    int d = ty + i * 4;
    v_t[((size_t)kvh * HD + d0 + d) * S_LEN + s0 + tx] = tile[tx][d];
  }
}

// ============ 128 x 192 GEMM FN=3, 2 blocks/CU (round-10/15 PROVEN) — QKV proj ============
// acc 48 + operand 40 + addr ~= 100 VGPR: fits 128 cap. (K-split 64x96 needs 136 -> spills.)
__global__ __launch_bounds__(512, 4) void k_g128x3(const unsigned short* __restrict__ A,
                                                   const unsigned short* __restrict__ B,
                                                   unsigned short* __restrict__ C,
                                                   int M, int N, int K) {
  constexpr int FN = 3;
  extern __shared__ __align__(16) unsigned short smem[];
  char* Sc = (char*)smem;
  const int tid = threadIdx.x;
  const int wvid = tid >> 6, l = tid & 63;
  const int wm = wvid >> 2, wn = wvid & 3;
  const int l15 = l & 15, l4 = l >> 4;

  const int cpx = gridDim.x >> 3;
  const int swz = (blockIdx.x & 7) * cpx + (blockIdx.x >> 3);
  const int mtiles = M >> 7;
  const int m0 = (swz % mtiles) * 128;
  const int n0 = (swz / mtiles) * (FN * 64);

  const int NT = K >> 6;

  const int rsw = (l15 & 7) << 4;
  const int a_base = (wm * 64 + l15) * 128;
  const int b_base = (wn * FN * 16 + l15) * 128;
  const int c0 = (l4 * 16) ^ rsw;
  const int c1 = (64 + l4 * 16) ^ rsw;

  const int srow = l >> 3;
  const int st_k8 = (l & 7) ^ (srow & 7);

  auto stA = [&](int tt) {
    if (tt >= NT) return;
    const unsigned short* g = A + (size_t)(m0 + wvid * 8 + srow) * K + tt * 64 + st_k8 * 8;
    char* lb = Sc + (tt & 1) * 16384 + wvid * 1024;
#pragma unroll
    for (int j = 0; j < 2; ++j)
      gl16(g + (size_t)(j * 64) * K, (unsigned short*)(lb + j * 8192));
  };
  auto stB = [&](int tt) {
    if (tt >= NT) return;
    const unsigned short* g = B + (size_t)(n0 + wvid * 8 + srow) * K + tt * 64 + st_k8 * 8;
    char* lb = Sc + 32768 + (tt & 1) * (FN * 8192) + wvid * 1024;
#pragma unroll
    for (int j = 0; j < FN; ++j)
      gl16(g + (size_t)(j * 64) * K, (unsigned short*)(lb + j * 8192));
  };

  f32x4 acc[4][FN] = {};

  stA(0); stB(0); stA(1);
  if (NT > 1) asm volatile("s_waitcnt vmcnt(2)" ::: "memory");
  else        asm volatile("s_waitcnt vmcnt(0)" ::: "memory");
  __builtin_amdgcn_s_barrier();

  for (int t = 0; t < NT; ++t) {
    const char* Ab = Sc + (t & 1) * 16384;
    const char* Bb = Sc + 32768 + (t & 1) * (FN * 8192);
    stB(t + 1);
    bf16x8 a[4], b[FN];
#pragma unroll
    for (int fm = 0; fm < 4; ++fm) a[fm] = *(const bf16x8*)(Ab + a_base + fm * 2048 + c0);
#pragma unroll
    for (int fn = 0; fn < FN; ++fn) b[fn] = *(const bf16x8*)(Bb + b_base + fn * 2048 + c0);
    __builtin_amdgcn_s_setprio(1);
#pragma unroll
    for (int fm = 0; fm < 4; ++fm)
#pragma unroll
      for (int fn = 0; fn < FN; ++fn)
        acc[fm][fn] = __builtin_amdgcn_mfma_f32_16x16x32_bf16(a[fm], b[fn], acc[fm][fn], 0, 0, 0);
    __builtin_amdgcn_s_setprio(0);
#pragma unroll
    for (int fm = 0; fm < 4; ++fm) a[fm] = *(const bf16x8*)(Ab + a_base + fm * 2048 + c1);
#pragma unroll
    for (int fn = 0; fn < FN; ++fn) b[fn] = *(const bf16x8*)(Bb + b_base + fn * 2048 + c1);
    __builtin_amdgcn_s_setprio(1);
#pragma unroll
    for (int fm = 0; fm < 4; ++fm)
#pragma unroll
      for (int fn = 0; fn < FN; ++fn)
        acc[fm][fn] = __builtin_amdgcn_mfma_f32_16x16x32_bf16(a[fm], b[fn], acc[fm][fn], 0, 0, 0);
    __builtin_amdgcn_s_setprio(0);
    __builtin_amdgcn_s_barrier();
    stA(t + 2);
    if (t + 1 < NT) {
      if (t + 1 == NT - 1) asm volatile("s_waitcnt vmcnt(0)" ::: "memory");
      else                 asm volatile("s_waitcnt vmcnt(2)" ::: "memory");
      __builtin_amdgcn_s_barrier();
    }
  }

#pragma unroll
  for (int fm = 0; fm < 4; ++fm) {
    int row0 = m0 + wm * 64 + fm * 16 + l4 * 4;
#pragma unroll
    for (int fn = 0; fn < FN; ++fn) {
      int col = n0 + wn * FN * 16 + fn * 16 + l15;
#pragma unroll
      for (int r = 0; r < 4; ++r)
        C[(size_t)(row0 + r) * N + col] = f2b(acc[fm][fn][r]);
    }
  }
}

// ===== 128 x 128 GEMM, K-SPLIT waves, per-wave 64x64 — out proj (round-15 proven) =====
// acc 64 + operand 32 ~= 105 VGPR: fits. reads/MFMA 0.5.
__global__ __launch_bounds__(512, 4) void k_gksplit(const unsigned short* __restrict__ A,
                                                    const unsigned short* __restrict__ B,
                                                    float* __restrict__ C,
                                                    int M, int N, int K) {
  extern __shared__ __align__(16) unsigned short smem[];
  char* Sc = (char*)smem;
  const int tid = threadIdx.x;
  const int wvid = tid >> 6, l = tid & 63;
  const int wm = wvid & 1, wn = (wvid >> 1) & 1, wk = wvid >> 2;
  const int l15 = l & 15, l4 = l >> 4;

  const int cpx = gridDim.x >> 3;
  const int swz = (blockIdx.x & 7) * cpx + (blockIdx.x >> 3);
  const int mtiles = M >> 7;
  const int m0 = (swz % mtiles) * 128;
  const int n0 = (swz / mtiles) * 128;

  const int NT = K >> 6;

  const int rsw = (l15 & 7) << 4;
  const int a_base = (wm * 64 + l15) * 128;
  const int b_base = (wn * 64 + l15) * 128;
  const int ck = (wk * 64 + l4 * 16) ^ rsw;

  const int srow = l >> 3;
  const int st_k8 = (l & 7) ^ (srow & 7);

  auto stA = [&](int tt) {
    if (tt >= NT) return;
    const unsigned short* g = A + (size_t)(m0 + wvid * 8 + srow) * K + tt * 64 + st_k8 * 8;
    char* lb = Sc + (tt & 1) * 16384 + wvid * 1024;
#pragma unroll
    for (int j = 0; j < 2; ++j)
      gl16(g + (size_t)(j * 64) * K, (unsigned short*)(lb + j * 8192));
  };
  auto stB = [&](int tt) {
    if (tt >= NT) return;
    const unsigned short* g = B + (size_t)(n0 + wvid * 8 + srow) * K + tt * 64 + st_k8 * 8;
    char* lb = Sc + 32768 + (tt & 1) * 16384 + wvid * 1024;
#pragma unroll
    for (int j = 0; j < 2; ++j)
      gl16(g + (size_t)(j * 64) * K, (unsigned short*)(lb + j * 8192));
  };

  f32x4 acc[4][4] = {};

  stA(0); stB(0); stA(1);
  if (NT > 1) asm volatile("s_waitcnt vmcnt(2)" ::: "memory");
  else        asm volatile("s_waitcnt vmcnt(0)" ::: "memory");
  __builtin_amdgcn_s_barrier();

  for (int t = 0; t < NT; ++t) {
    const char* Ab = Sc + (t & 1) * 16384;
    const char* Bb = Sc + 32768 + (t & 1) * 16384;
    stB(t + 1);
    bf16x8 a[4], b[4];
#pragma unroll
    for (int fm = 0; fm < 4; ++fm) a[fm] = *(const bf16x8*)(Ab + a_base + fm * 2048 + ck);
#pragma unroll
    for (int fn = 0; fn < 4; ++fn) b[fn] = *(const bf16x8*)(Bb + b_base + fn * 2048 + ck);
    __builtin_amdgcn_s_setprio(1);
#pragma unroll
    for (int fm = 0; fm < 4; ++fm)
#pragma unroll
      for (int fn = 0; fn < 4; ++fn)
        acc[fm][fn] = __builtin_amdgcn_mfma_f32_16x16x32_bf16(a[fm], b[fn], acc[fm][fn], 0, 0, 0);
    __builtin_amdgcn_s_setprio(0);
    __builtin_amdgcn_s_barrier();
    stA(t + 2);
    if (t + 1 < NT) {
      if (t + 1 == NT - 1) asm volatile("s_waitcnt vmcnt(0)" ::: "memory");
      else                 asm volatile("s_waitcnt vmcnt(2)" ::: "memory");
      __builtin_amdgcn_s_barrier();
    }
  }

  char* xch = Sc + (wm * 2 + wn) * 16384;
  if (wk == 1) {
#pragma unroll
    for (int fm = 0; fm < 4; ++fm)
#pragma unroll
      for (int fn = 0; fn < 4; ++fn)
        *(f32x4*)(xch + (fm * 4 + fn) * 1024 + l * 16) = acc[fm][fn];
  }
  __syncthreads();
  if (wk == 0) {
#pragma unroll
    for (int fm = 0; fm < 4; ++fm) {
      int row0 = m0 + wm * 64 + fm * 16 + l4 * 4;
#pragma unroll
      for (int fn = 0; fn < 4; ++fn) {
        f32x4 o = *(const f32x4*)(xch + (fm * 4 + fn) * 1024 + l * 16);
        int col = n0 + wn * 64 + fn * 16 + l15;
#pragma unroll
        for (int r = 0; r < 4; ++r)
          C[(size_t)(row0 + r) * N + col] = acc[fm][fn][r] + o[r];
      }
    }
  }
}

// ------------- causal GQA flash attention (round-14 proven) -------------
__global__ __launch_bounds__(512, 4) void k_attn(const unsigned short* __restrict__ q_int,
                                                 const float* __restrict__ q_ds_t,
                                                 const unsigned short* __restrict__ k_int,
                                                 const float* __restrict__ k_ds_t,
                                                 const unsigned short* __restrict__ v_t,
                                                 unsigned short* __restrict__ o_bf) {
  __shared__ __align__(16) unsigned short K_lds[2][8192];
  __shared__ __align__(16) unsigned short V_lds[2][8192];
  __shared__ __align__(16) unsigned short P_lds[8][1024];

  const int bid = blockIdx.x;
  const int kvh = bid & 7;
  const int qt = 63 - (bid >> 3);
  const int tid = threadIdx.x, wv = tid >> 6, l = tid & 63;
  const int l15 = l & 15, l4 = l >> 4;
  const int h = kvh * 4 + (wv & 3);
  const int rh = wv >> 2;

  auto stage = [&](int b, int kt) {
    const unsigned short* kB = k_int + (size_t)kt * 64 * (NKV * HD) + kvh * HD;
    const unsigned short* vB = v_t + (size_t)kvh * HD * S_LEN + (size_t)kt * 64;
#pragma unroll
    for (int j = 0; j < 2; ++j) {
      int wi = j * 8 + wv;
      int slot = wi * 64 + l;
      int key = slot >> 4;
      int colb = ((slot & 15) * 16) ^ ((key & 7) << 4);
      gl16(kB + key * (NKV * HD) + (colb >> 1), &K_lds[b][wi * 512]);
      int d = slot >> 3;
      int ckb = ((slot & 7) * 16) ^ ((d & 7) << 4);
      gl16(vB + (size_t)d * S_LEN + (ckb >> 1), &V_lds[b][wi * 512]);
    }
  };

  const int qrow_lo = qt * 32 + rh * 16;
  const int qg = qrow_lo + l15;
  const int crow = qrow_lo + l4 * 4;

  bf16x8 qf[4];
  {
    const unsigned short* qp = q_int + ((size_t)qg * NH + h) * HD + l4 * 8;
#pragma unroll
    for (int kd = 0; kd < 4; ++kd) qf[kd] = *(const bf16x8*)(qp + kd * 32);
  }
  const float qsS = ATT_SCALE_L2E * q_ds_t[(size_t)h * S_LEN + qg];

  float m_run = -3.0e38f, l_run = 0.f;
  f32x4 o_acc[8] = {};

  const int nkt = (qt >> 1) + 1;
  stage(0, 0);
  __syncthreads();

  const int psw = (l15 & 7) << 4;

  auto tileBody = [&](auto mc, int kt) {
    constexpr bool MASKED = decltype(mc)::value;
    const int cur = kt & 1;
    f32x4 ksd[4];
    {
      const f32x4* kdp = (const f32x4*)(k_ds_t + (size_t)kvh * S_LEN + kt * 64 + l4 * 4);
#pragma unroll
      for (int nt = 0; nt < 4; ++nt) ksd[nt] = kdp[nt * 4];
    }
    if (kt + 1 < nkt) stage(cur ^ 1, kt + 1);

    f32x4 sacc[4] = {};
#pragma unroll
    for (int nt = 0; nt < 4; ++nt) {
      int key = nt * 16 + l15;
#pragma unroll
      for (int kd = 0; kd < 4; ++kd) {
        int byte = key * 256 + kd * 64 + l4 * 16;
        byte ^= (key & 7) << 4;
        bf16x8 kf = *(const bf16x8*)((const char*)&K_lds[cur][0] + byte);
        sacc[nt] = __builtin_amdgcn_mfma_f32_16x16x32_bf16(kf, qf[kd], sacc[nt], 0, 0, 0);
      }
    }

    float p[4][4];
    float tmax = -3.0e38f;
#pragma unroll
    for (int nt = 0; nt < 4; ++nt) {
#pragma unroll
      for (int r = 0; r < 4; ++r) {
        float sc = sacc[nt][r] * (qsS * ksd[nt][r]);
        if constexpr (MASKED) {
          int keyg = kt * 64 + nt * 16 + l4 * 4 + r;
          sc = (keyg <= qg) ? sc : -3.0e38f;
        }
        p[nt][r] = sc;
        tmax = fmaxf(tmax, sc);
      }
    }
    tmax = fmaxf(tmax, __shfl_xor(tmax, 16));
    tmax = fmaxf(tmax, __shfl_xor(tmax, 32));

    float nm = fmaxf(m_run, tmax);
    bool need = tmax > m_run + 11.0f;
    if (__ballot(need)) {
      float corr = __builtin_amdgcn_exp2f(m_run - nm);
      m_run = nm;
      l_run *= corr;
      float cq[4];
#pragma unroll
      for (int r = 0; r < 4; ++r) cq[r] = __shfl(corr, (l & 48) | (l4 * 4 + r));
#pragma unroll
      for (int dt = 0; dt < 8; ++dt)
#pragma unroll
        for (int r = 0; r < 4; ++r) o_acc[dt][r] *= cq[r];
    }

    float psum = 0.f;
#pragma unroll
    for (int nt = 0; nt < 4; ++nt)
#pragma unroll
      for (int r = 0; r < 4; ++r) {
        float e = __builtin_amdgcn_exp2f(p[nt][r] - m_run);
        p[nt][r] = e;
        psum += e;
      }
    psum += __shfl_xor(psum, 16);
    psum += __shfl_xor(psum, 32);
    l_run += psum;

#pragma unroll
    for (int nt = 0; nt < 4; ++nt) {
      bf16x4 pk;
      pk[0] = (__bf16)p[nt][0]; pk[1] = (__bf16)p[nt][1];
      pk[2] = (__bf16)p[nt][2]; pk[3] = (__bf16)p[nt][3];
      int bw = l15 * 128 + ((nt * 32 + l4 * 8) ^ psw);
      *(bf16x4*)((char*)&P_lds[wv][0] + bw) = pk;
    }
    bf16x8 pa[2];
#pragma unroll
    for (int kc = 0; kc < 2; ++kc) {
      int br = l15 * 128 + ((kc * 64 + l4 * 16) ^ psw);
      pa[kc] = *(const bf16x8*)((const char*)&P_lds[wv][0] + br);
    }

#pragma unroll
    for (int dt = 0; dt < 8; ++dt) {
      int d = dt * 16 + l15;
      int swzv = (d & 7) << 4;
#pragma unroll
      for (int kc = 0; kc < 2; ++kc) {
        int byte = d * 128 + ((kc * 64 + l4 * 16) ^ swzv);
        bf16x8 vb = *(const bf16x8*)((const char*)&V_lds[cur][0] + byte);
        o_acc[dt] = __builtin_amdgcn_mfma_f32_16x16x32_bf16(pa[kc], vb, o_acc[dt], 0, 0, 0);
      }
    }
    __syncthreads();
  };

  for (int kt = 0; kt + 1 < nkt; ++kt) tileBody(BoolC<false>{}, kt);
  tileBody(BoolC<true>{}, nkt - 1);

  float inv = 1.0f / l_run;
  float invq[4];
#pragma unroll
  for (int r = 0; r < 4; ++r) invq[r] = __shfl(inv, (l & 48) | (l4 * 4 + r));
#pragma unroll
  for (int dt = 0; dt < 8; ++dt)
#pragma unroll
    for (int r = 0; r < 4; ++r)
      o_bf[(size_t)(crow + r) * (NH * HD) + h * HD + dt * 16 + l15] =
          f2b(o_acc[dt][r] * invq[r]);
}

extern "C" void kernel_launch(void* const* d_in, const int* in_sizes, int n_in,
                              void* d_out, int out_size, void* d_ws, size_t ws_size,
                              hipStream_t stream) {
  const float* x    = (const float*)d_in[0];
  const float* Wq   = (const float*)d_in[1];
  const float* Wk   = (const float*)d_in[2];
  const float* Wv   = (const float*)d_in[3];
  const float* Wo   = (const float*)d_in[4];
  const float* cost = (const float*)d_in[5];
  const float* sint = (const float*)d_in[6];
  float* out = (float*)d_out;
  char* ws = (char*)d_ws;

  unsigned short* xb     = (unsigned short*)(ws);                 // 16 MB (dead after gemm1)
  unsigned short* wqkv_t = (unsigned short*)(ws + 16777216);      // 48 MB (dead after gemm1)
  unsigned short* wo_t   = (unsigned short*)(ws + 67108864);      // 32 MB (4096x4096)
  unsigned short* qkv    = (unsigned short*)(ws + 100663296);     // 24 MB bf16
  unsigned short* q_int  = (unsigned short*)(ws + 150994944);     // 16 MB
  unsigned short* k_int  = (unsigned short*)(ws + 167772160);     // 4 MB
  float*          q_ds_t = (float*)(ws + 176160768);              // 256 KB [NH][S]
  float*          k_ds_t = (float*)(ws + 176422912);              // 64 KB  [NKV][S]
  unsigned short* o_bf   = (unsigned short*)(ws + 176488448);     // 16 MB
  unsigned short* v_t    = (unsigned short*)(ws);                 // 4 MB, aliases dead xb

  hipFuncSetAttribute((const void*)k_g128x3,
                      hipFuncAttributeMaxDynamicSharedMemorySize, 81920);
  hipFuncSetAttribute((const void*)k_gksplit,
                      hipFuncAttributeMaxDynamicSharedMemorySize, 65536);

  // merged prep: cvt_x + Wq/Wk/Wv/Wo transposes in one launch
  k_prep<<<dim3(18432), 256, 0, stream>>>(x, Wq, Wk, Wv, Wo, xb, wqkv_t, wo_t);
  // QKV proj: 128x192 tiles -> 512 blocks = 2 blocks/CU; bf16 output (round-15 proven)
  k_g128x3<<<dim3(512), 512, 81920, stream>>>(xb, wqkv_t, qkv, 2048, 6144, 4096);
  // merged post: RoPE+quant (q,k) + V^T transpose in one launch
  k_post<<<dim3(20992), 256, 0, stream>>>(qkv, cost, sint, q_int, q_ds_t, k_int, k_ds_t, v_t);
  // attention: 512 blocks x 512 threads (4 heads x 32 q-rows each), mask-elided tiles
  k_attn<<<dim3(512), 512, 0, stream>>>(q_int, q_ds_t, k_int, k_ds_t, v_t, o_bf);
  // out proj: 128x128 tiles, K-split waves (per-wave 64x64) -> 512 blocks = 2/CU
  k_gksplit<<<dim3(512), 512, 65536, stream>>>(o_bf, wo_t, out, 2048, 4096, 4096);
}

// Round 18
// 288.535 us; speedup vs baseline: 2.5125x; 1.0631x over previous
//
#include <hip/hip_runtime.h>
#include <hip/hip_bf16.h>

#define S_LEN 2048
#define DMODEL 4096
#define NH 32
#define NKV 8
#define HD 128
#define NQKV 6144
#define VOFF (DMODEL + NKV * HD)  // v-section offset inside a qkv row
// 1/sqrt(128) * log2(e): scores in log2 domain so v_exp_f32 (=2^x) is the exp
#define ATT_SCALE_L2E 0.1275175213528852f

typedef __bf16 bf16x8 __attribute__((ext_vector_type(8)));
typedef __bf16 bf16x4 __attribute__((ext_vector_type(4)));
typedef float f32x4 __attribute__((ext_vector_type(4)));
typedef int i32x4 __attribute__((ext_vector_type(4)));

template <bool B> struct BoolC { static constexpr bool value = B; };

// float -> bf16 bits, round-to-nearest-even
__device__ __forceinline__ unsigned short f2b(float f) {
  union { float f; unsigned u; } a; a.f = f;
  unsigned u = a.u;
  return (unsigned short)((u + 0x7FFFu + ((u >> 16) & 1u)) >> 16);
}
// bf16 bits -> float
__device__ __forceinline__ float b2f(unsigned short u) {
  union { unsigned u; float f; } a; a.u = (unsigned)u << 16; return a.f;
}

__device__ __forceinline__ void gl16(const void* g, void* l) {
  __builtin_amdgcn_global_load_lds(
      (const __attribute__((address_space(1))) unsigned int*)g,
      (__attribute__((address_space(3))) unsigned int*)l, 16, 0, 0);
}

// ============ merged prep: x fp32->bf16 + 4 weight transposes (one launch) ============
__global__ __launch_bounds__(256) void k_prep(const float* __restrict__ x,
                                              const float* __restrict__ Wq,
                                              const float* __restrict__ Wk,
                                              const float* __restrict__ Wv,
                                              const float* __restrict__ Wo,
                                              unsigned short* __restrict__ xb,
                                              unsigned short* __restrict__ wqkv_t,
                                              unsigned short* __restrict__ wo_t) {
  __shared__ float tile[64][65];
  const int id = blockIdx.x;
  if (id >= 10240) {  // ---- cvt_x ----
    int i = (id - 10240) * 256 + threadIdx.x;
    float4 v = ((const float4*)x)[i];
    ushort4 o;
    o.x = f2b(v.x); o.y = f2b(v.y); o.z = f2b(v.z); o.w = f2b(v.w);
    ((ushort4*)xb)[i] = o;
    return;
  }
  const float* W;
  unsigned short* Wt;
  int N, bx, by;
  if (id < 4096)      { W = Wq; Wt = wqkv_t;                         N = 4096; bx = id & 63;          by = id >> 6; }
  else if (id < 5120) { W = Wk; Wt = wqkv_t + (size_t)4096 * 4096;   N = 1024; bx = (id - 4096) & 63; by = (id - 4096) >> 6; }
  else if (id < 6144) { W = Wv; Wt = wqkv_t + (size_t)5120 * 4096;   N = 1024; bx = (id - 5120) & 63; by = (id - 5120) >> 6; }
  else                { W = Wo; Wt = wo_t;                           N = 4096; bx = (id - 6144) & 63; by = (id - 6144) >> 6; }
  const int k0 = bx * 64, n0 = by * 64;
  const int tx = threadIdx.x & 31, ty = threadIdx.x >> 5;
#pragma unroll
  for (int i = 0; i < 8; ++i) {
    int k = ty + i * 8;
    const float* src = W + (size_t)(k0 + k) * N + n0;
    tile[k][tx] = src[tx];
    tile[k][tx + 32] = src[tx + 32];
  }
  __syncthreads();
  int kq = threadIdx.x & 15, nb = threadIdx.x >> 4;
#pragma unroll
  for (int i = 0; i < 4; ++i) {
    int n = nb + i * 16;
    ushort4 o;
    o.x = f2b(tile[kq * 4 + 0][n]);
    o.y = f2b(tile[kq * 4 + 1][n]);
    o.z = f2b(tile[kq * 4 + 2][n]);
    o.w = f2b(tile[kq * 4 + 3][n]);
    *(ushort4*)&Wt[(size_t)(n0 + n) * 4096 + k0 + kq * 4] = o;
  }
}

// ============ merged post-proj: RoPE + INT8 quant (q,k as bytes) + V^T transpose ============
__global__ __launch_bounds__(256) void k_post(const unsigned short* __restrict__ qkv,
                                              const float* __restrict__ cost,
                                              const float* __restrict__ sint,
                                              signed char* __restrict__ q_i8,
                                              float* __restrict__ q_ds_t,
                                              signed char* __restrict__ k_i8,
                                              float* __restrict__ k_ds_t,
                                              unsigned short* __restrict__ v_t) {
  __shared__ unsigned short tile[64][65];
  const int id = blockIdx.x;
  if (id < 20480) {
    int y = id >> 11, s = id & 2047;
    int wv = threadIdx.x >> 6, l = threadIdx.x & 63;
    int hh = y * 4 + wv;
    const unsigned short* row = qkv + (size_t)s * NQKV;
    int off = (hh < NH) ? hh * HD : DMODEL + (hh - NH) * HD;
    float t1 = b2f(row[off + l]), t2 = b2f(row[off + 64 + l]);
    float c1 = cost[s * HD + l],      sn1 = sint[s * HD + l];
    float c2 = cost[s * HD + 64 + l], sn2 = sint[s * HD + 64 + l];
    float o1 = t1 * c1 - t2 * sn1;
    float o2 = t2 * c2 + t1 * sn2;
    float amax = fmaxf(fabsf(o1), fabsf(o2));
#pragma unroll
    for (int m = 1; m < 64; m <<= 1) amax = fmaxf(amax, __shfl_xor(amax, m));
    amax = fmaxf(amax, 1e-5f);
    float scale = 127.0f / amax;
    float dscale = amax * (1.0f / 127.0f);
    float v1 = fminf(fmaxf(rintf(o1 * scale), -128.f), 127.f);
    float v2 = fminf(fmaxf(rintf(o2 * scale), -128.f), 127.f);
    if (hh < NH) {
      signed char* dst = q_i8 + ((size_t)s * NH + hh) * HD;
      dst[l] = (signed char)v1; dst[l + 64] = (signed char)v2;
      if (l == 0) q_ds_t[(size_t)hh * S_LEN + s] = dscale;
    } else {
      int kh = hh - NH;
      signed char* dst = k_i8 + ((size_t)s * NKV + kh) * HD;
      dst[l] = (signed char)v1; dst[l + 64] = (signed char)v2;
      if (l == 0) k_ds_t[(size_t)kh * S_LEN + s] = dscale;
    }
    return;
  }
  int vid = id - 20480;
  int s0 = (vid & 31) * 64, d0 = ((vid >> 5) & 1) * 64, kvh = vid >> 6;
  int tx = threadIdx.x & 63, ty = threadIdx.x >> 6;
#pragma unroll
  for (int i = 0; i < 16; ++i) {
    int s = ty + i * 4;
    tile[s][tx] = qkv[(size_t)(s0 + s) * NQKV + VOFF + kvh * HD + d0 + tx];
  }
  __syncthreads();
#pragma unroll
  for (int i = 0; i < 16; ++i) {
    int d = ty + i * 4;
    v_t[((size_t)kvh * HD + d0 + d) * S_LEN + s0 + tx] = tile[tx][d];
  }
}

// ============ 128 x 192 GEMM FN=3, 2 blocks/CU (PROVEN) — QKV proj ============
__global__ __launch_bounds__(512, 4) void k_g128x3(const unsigned short* __restrict__ A,
                                                   const unsigned short* __restrict__ B,
                                                   unsigned short* __restrict__ C,
                                                   int M, int N, int K) {
  constexpr int FN = 3;
  extern __shared__ __align__(16) unsigned short smem[];
  char* Sc = (char*)smem;
  const int tid = threadIdx.x;
  const int wvid = tid >> 6, l = tid & 63;
  const int wm = wvid >> 2, wn = wvid & 3;
  const int l15 = l & 15, l4 = l >> 4;

  const int cpx = gridDim.x >> 3;
  const int swz = (blockIdx.x & 7) * cpx + (blockIdx.x >> 3);
  const int mtiles = M >> 7;
  const int m0 = (swz % mtiles) * 128;
  const int n0 = (swz / mtiles) * (FN * 64);

  const int NT = K >> 6;

  const int rsw = (l15 & 7) << 4;
  const int a_base = (wm * 64 + l15) * 128;
  const int b_base = (wn * FN * 16 + l15) * 128;
  const int c0 = (l4 * 16) ^ rsw;
  const int c1 = (64 + l4 * 16) ^ rsw;

  const int srow = l >> 3;
  const int st_k8 = (l & 7) ^ (srow & 7);

  auto stA = [&](int tt) {
    if (tt >= NT) return;
    const unsigned short* g = A + (size_t)(m0 + wvid * 8 + srow) * K + tt * 64 + st_k8 * 8;
    char* lb = Sc + (tt & 1) * 16384 + wvid * 1024;
#pragma unroll
    for (int j = 0; j < 2; ++j)
      gl16(g + (size_t)(j * 64) * K, (unsigned short*)(lb + j * 8192));
  };
  auto stB = [&](int tt) {
    if (tt >= NT) return;
    const unsigned short* g = B + (size_t)(n0 + wvid * 8 + srow) * K + tt * 64 + st_k8 * 8;
    char* lb = Sc + 32768 + (tt & 1) * (FN * 8192) + wvid * 1024;
#pragma unroll
    for (int j = 0; j < FN; ++j)
      gl16(g + (size_t)(j * 64) * K, (unsigned short*)(lb + j * 8192));
  };

  f32x4 acc[4][FN] = {};

  stA(0); stB(0); stA(1);
  if (NT > 1) asm volatile("s_waitcnt vmcnt(2)" ::: "memory");
  else        asm volatile("s_waitcnt vmcnt(0)" ::: "memory");
  __builtin_amdgcn_s_barrier();

  for (int t = 0; t < NT; ++t) {
    const char* Ab = Sc + (t & 1) * 16384;
    const char* Bb = Sc + 32768 + (t & 1) * (FN * 8192);
    stB(t + 1);
    bf16x8 a[4], b[FN];
#pragma unroll
    for (int fm = 0; fm < 4; ++fm) a[fm] = *(const bf16x8*)(Ab + a_base + fm * 2048 + c0);
#pragma unroll
    for (int fn = 0; fn < FN; ++fn) b[fn] = *(const bf16x8*)(Bb + b_base + fn * 2048 + c0);
    __builtin_amdgcn_s_setprio(1);
#pragma unroll
    for (int fm = 0; fm < 4; ++fm)
#pragma unroll
      for (int fn = 0; fn < FN; ++fn)
        acc[fm][fn] = __builtin_amdgcn_mfma_f32_16x16x32_bf16(a[fm], b[fn], acc[fm][fn], 0, 0, 0);
    __builtin_amdgcn_s_setprio(0);
#pragma unroll
    for (int fm = 0; fm < 4; ++fm) a[fm] = *(const bf16x8*)(Ab + a_base + fm * 2048 + c1);
#pragma unroll
    for (int fn = 0; fn < FN; ++fn) b[fn] = *(const bf16x8*)(Bb + b_base + fn * 2048 + c1);
    __builtin_amdgcn_s_setprio(1);
#pragma unroll
    for (int fm = 0; fm < 4; ++fm)
#pragma unroll
      for (int fn = 0; fn < FN; ++fn)
        acc[fm][fn] = __builtin_amdgcn_mfma_f32_16x16x32_bf16(a[fm], b[fn], acc[fm][fn], 0, 0, 0);
    __builtin_amdgcn_s_setprio(0);
    __builtin_amdgcn_s_barrier();
    stA(t + 2);
    if (t + 1 < NT) {
      if (t + 1 == NT - 1) asm volatile("s_waitcnt vmcnt(0)" ::: "memory");
      else                 asm volatile("s_waitcnt vmcnt(2)" ::: "memory");
      __builtin_amdgcn_s_barrier();
    }
  }

#pragma unroll
  for (int fm = 0; fm < 4; ++fm) {
    int row0 = m0 + wm * 64 + fm * 16 + l4 * 4;
#pragma unroll
    for (int fn = 0; fn < FN; ++fn) {
      int col = n0 + wn * FN * 16 + fn * 16 + l15;
#pragma unroll
      for (int r = 0; r < 4; ++r)
        C[(size_t)(row0 + r) * N + col] = f2b(acc[fm][fn][r]);
    }
  }
}

// ===== 128 x 128 GEMM, K-SPLIT waves, per-wave 64x64 — out proj (PROVEN) =====
__global__ __launch_bounds__(512, 4) void k_gksplit(const unsigned short* __restrict__ A,
                                                    const unsigned short* __restrict__ B,
                                                    float* __restrict__ C,
                                                    int M, int N, int K) {
  extern __shared__ __align__(16) unsigned short smem[];
  char* Sc = (char*)smem;
  const int tid = threadIdx.x;
  const int wvid = tid >> 6, l = tid & 63;
  const int wm = wvid & 1, wn = (wvid >> 1) & 1, wk = wvid >> 2;
  const int l15 = l & 15, l4 = l >> 4;

  const int cpx = gridDim.x >> 3;
  const int swz = (blockIdx.x & 7) * cpx + (blockIdx.x >> 3);
  const int mtiles = M >> 7;
  const int m0 = (swz % mtiles) * 128;
  const int n0 = (swz / mtiles) * 128;

  const int NT = K >> 6;

  const int rsw = (l15 & 7) << 4;
  const int a_base = (wm * 64 + l15) * 128;
  const int b_base = (wn * 64 + l15) * 128;
  const int ck = (wk * 64 + l4 * 16) ^ rsw;

  const int srow = l >> 3;
  const int st_k8 = (l & 7) ^ (srow & 7);

  auto stA = [&](int tt) {
    if (tt >= NT) return;
    const unsigned short* g = A + (size_t)(m0 + wvid * 8 + srow) * K + tt * 64 + st_k8 * 8;
    char* lb = Sc + (tt & 1) * 16384 + wvid * 1024;
#pragma unroll
    for (int j = 0; j < 2; ++j)
      gl16(g + (size_t)(j * 64) * K, (unsigned short*)(lb + j * 8192));
  };
  auto stB = [&](int tt) {
    if (tt >= NT) return;
    const unsigned short* g = B + (size_t)(n0 + wvid * 8 + srow) * K + tt * 64 + st_k8 * 8;
    char* lb = Sc + 32768 + (tt & 1) * 16384 + wvid * 1024;
#pragma unroll
    for (int j = 0; j < 2; ++j)
      gl16(g + (size_t)(j * 64) * K, (unsigned short*)(lb + j * 8192));
  };

  f32x4 acc[4][4] = {};

  stA(0); stB(0); stA(1);
  if (NT > 1) asm volatile("s_waitcnt vmcnt(2)" ::: "memory");
  else        asm volatile("s_waitcnt vmcnt(0)" ::: "memory");
  __builtin_amdgcn_s_barrier();

  for (int t = 0; t < NT; ++t) {
    const char* Ab = Sc + (t & 1) * 16384;
    const char* Bb = Sc + 32768 + (t & 1) * 16384;
    stB(t + 1);
    bf16x8 a[4], b[4];
#pragma unroll
    for (int fm = 0; fm < 4; ++fm) a[fm] = *(const bf16x8*)(Ab + a_base + fm * 2048 + ck);
#pragma unroll
    for (int fn = 0; fn < 4; ++fn) b[fn] = *(const bf16x8*)(Bb + b_base + fn * 2048 + ck);
    __builtin_amdgcn_s_setprio(1);
#pragma unroll
    for (int fm = 0; fm < 4; ++fm)
#pragma unroll
      for (int fn = 0; fn < 4; ++fn)
        acc[fm][fn] = __builtin_amdgcn_mfma_f32_16x16x32_bf16(a[fm], b[fn], acc[fm][fn], 0, 0, 0);
    __builtin_amdgcn_s_setprio(0);
    __builtin_amdgcn_s_barrier();
    stA(t + 2);
    if (t + 1 < NT) {
      if (t + 1 == NT - 1) asm volatile("s_waitcnt vmcnt(0)" ::: "memory");
      else                 asm volatile("s_waitcnt vmcnt(2)" ::: "memory");
      __builtin_amdgcn_s_barrier();
    }
  }

  char* xch = Sc + (wm * 2 + wn) * 16384;
  if (wk == 1) {
#pragma unroll
    for (int fm = 0; fm < 4; ++fm)
#pragma unroll
      for (int fn = 0; fn < 4; ++fn)
        *(f32x4*)(xch + (fm * 4 + fn) * 1024 + l * 16) = acc[fm][fn];
  }
  __syncthreads();
  if (wk == 0) {
#pragma unroll
    for (int fm = 0; fm < 4; ++fm) {
      int row0 = m0 + wm * 64 + fm * 16 + l4 * 4;
#pragma unroll
      for (int fn = 0; fn < 4; ++fn) {
        f32x4 o = *(const f32x4*)(xch + (fm * 4 + fn) * 1024 + l * 16);
        int col = n0 + wn * 64 + fn * 16 + l15;
#pragma unroll
        for (int r = 0; r < 4; ++r)
          C[(size_t)(row0 + r) * N + col] = acc[fm][fn][r] + o[r];
      }
    }
  }
}

// ------------- causal GQA flash attention: i8 MFMA QK^T (K=64), bf16 PV -------------
// K stored as int8: tile 8 KB (G4-swizzled rows of 128 B); QK = 8 x mfma_i32_16x16x64_i8
// per wave per tile (was 16 bf16 MFMA + 16 KB); exact int32 scores -> exact f32 cvt.
__global__ __launch_bounds__(512, 4) void k_attn(const signed char* __restrict__ q_i8,
                                                 const float* __restrict__ q_ds_t,
                                                 const signed char* __restrict__ k_i8,
                                                 const float* __restrict__ k_ds_t,
                                                 const unsigned short* __restrict__ v_t,
                                                 unsigned short* __restrict__ o_bf) {
  __shared__ __align__(16) signed char K_lds[2][8192];      // 64 keys x 128 B int8
  __shared__ __align__(16) unsigned short V_lds[2][8192];   // 64 keys x 128 d bf16 (V^T rows)
  __shared__ __align__(16) unsigned short P_lds[8][1024];

  const int bid = blockIdx.x;
  const int kvh = bid & 7;
  const int qt = 63 - (bid >> 3);
  const int tid = threadIdx.x, wv = tid >> 6, l = tid & 63;
  const int l15 = l & 15, l4 = l >> 4;
  const int h = kvh * 4 + (wv & 3);
  const int rh = wv >> 2;

  auto stage = [&](int b, int kt) {
    // K: 512 granules (16 B), 1 per thread; linear dest, pre-swizzled source col
    {
      int key = tid >> 3, g = tid & 7;
      int colb = (g * 16) ^ ((key & 7) << 4);
      const signed char* src = k_i8 + ((size_t)(kt * 64 + key) * NKV + kvh) * HD + colb;
      gl16(src, &K_lds[b][tid * 16]);
    }
    // V: 1024 granules, 2 per thread (proven pattern)
    const unsigned short* vB = v_t + (size_t)kvh * HD * S_LEN + (size_t)kt * 64;
#pragma unroll
    for (int j = 0; j < 2; ++j) {
      int wi = j * 8 + wv;
      int slot = wi * 64 + l;
      int d = slot >> 3;
      int ckb = ((slot & 7) * 16) ^ ((d & 7) << 4);
      gl16(vB + (size_t)d * S_LEN + (ckb >> 1), &V_lds[b][wi * 512]);
    }
  };

  const int qrow_lo = qt * 32 + rh * 16;
  const int qg = qrow_lo + l15;
  const int crow = qrow_lo + l4 * 4;

  i32x4 qf[2];
  {
    const signed char* qp = q_i8 + ((size_t)qg * NH + h) * HD + l4 * 16;
    qf[0] = *(const i32x4*)(qp);
    qf[1] = *(const i32x4*)(qp + 64);
  }
  const float qsS = ATT_SCALE_L2E * q_ds_t[(size_t)h * S_LEN + qg];

  float m_run = -3.0e38f, l_run = 0.f;
  f32x4 o_acc[8] = {};

  const int nkt = (qt >> 1) + 1;
  stage(0, 0);
  __syncthreads();

  const int psw = (l15 & 7) << 4;

  auto tileBody = [&](auto mc, int kt) {
    constexpr bool MASKED = decltype(mc)::value;
    const int cur = kt & 1;
    f32x4 ksd[4];
    {
      const f32x4* kdp = (const f32x4*)(k_ds_t + (size_t)kvh * S_LEN + kt * 64 + l4 * 4);
#pragma unroll
      for (int nt = 0; nt < 4; ++nt) ksd[nt] = kdp[nt * 4];
    }
    if (kt + 1 < nkt) stage(cur ^ 1, kt + 1);

    // ---- swapped QK^T (i8, K=64): mfma(K,Q) -> S[key][q] int32 exact ----
    i32x4 sacc[4] = {};
#pragma unroll
    for (int nt = 0; nt < 4; ++nt) {
      int key = nt * 16 + l15;
#pragma unroll
      for (int kd = 0; kd < 2; ++kd) {
        int byte = key * 128 + kd * 64 + l4 * 16;
        byte ^= (key & 7) << 4;
        i32x4 kf = *(const i32x4*)(&K_lds[cur][0] + byte);
        sacc[nt] = __builtin_amdgcn_mfma_i32_16x16x64_i8(kf, qf[kd], sacc[nt], 0, 0, 0);
      }
    }

    float p[4][4];
    float tmax = -3.0e38f;
#pragma unroll
    for (int nt = 0; nt < 4; ++nt) {
#pragma unroll
      for (int r = 0; r < 4; ++r) {
        float sc = (float)sacc[nt][r] * (qsS * ksd[nt][r]);
        if constexpr (MASKED) {
          int keyg = kt * 64 + nt * 16 + l4 * 4 + r;
          sc = (keyg <= qg) ? sc : -3.0e38f;
        }
        p[nt][r] = sc;
        tmax = fmaxf(tmax, sc);
      }
    }
    tmax = fmaxf(tmax, __shfl_xor(tmax, 16));
    tmax = fmaxf(tmax, __shfl_xor(tmax, 32));

    float nm = fmaxf(m_run, tmax);
    bool need = tmax > m_run + 11.0f;
    if (__ballot(need)) {
      float corr = __builtin_amdgcn_exp2f(m_run - nm);
      m_run = nm;
      l_run *= corr;
      float cq[4];
#pragma unroll
      for (int r = 0; r < 4; ++r) cq[r] = __shfl(corr, (l & 48) | (l4 * 4 + r));
#pragma unroll
      for (int dt = 0; dt < 8; ++dt)
#pragma unroll
        for (int r = 0; r < 4; ++r) o_acc[dt][r] *= cq[r];
    }

    float psum = 0.f;
#pragma unroll
    for (int nt = 0; nt < 4; ++nt)
#pragma unroll
      for (int r = 0; r < 4; ++r) {
        float e = __builtin_amdgcn_exp2f(p[nt][r] - m_run);
        p[nt][r] = e;
        psum += e;
      }
    psum += __shfl_xor(psum, 16);
    psum += __shfl_xor(psum, 32);
    l_run += psum;

#pragma unroll
    for (int nt = 0; nt < 4; ++nt) {
      bf16x4 pk;
      pk[0] = (__bf16)p[nt][0]; pk[1] = (__bf16)p[nt][1];
      pk[2] = (__bf16)p[nt][2]; pk[3] = (__bf16)p[nt][3];
      int bw = l15 * 128 + ((nt * 32 + l4 * 8) ^ psw);
      *(bf16x4*)((char*)&P_lds[wv][0] + bw) = pk;
    }
    bf16x8 pa[2];
#pragma unroll
    for (int kc = 0; kc < 2; ++kc) {
      int br = l15 * 128 + ((kc * 64 + l4 * 16) ^ psw);
      pa[kc] = *(const bf16x8*)((const char*)&P_lds[wv][0] + br);
    }

#pragma unroll
    for (int dt = 0; dt < 8; ++dt) {
      int d = dt * 16 + l15;
      int swzv = (d & 7) << 4;
#pragma unroll
      for (int kc = 0; kc < 2; ++kc) {
        int byte = d * 128 + ((kc * 64 + l4 * 16) ^ swzv);
        bf16x8 vb = *(const bf16x8*)((const char*)&V_lds[cur][0] + byte);
        o_acc[dt] = __builtin_amdgcn_mfma_f32_16x16x32_bf16(pa[kc], vb, o_acc[dt], 0, 0, 0);
      }
    }
    __syncthreads();
  };

  for (int kt = 0; kt + 1 < nkt; ++kt) tileBody(BoolC<false>{}, kt);
  tileBody(BoolC<true>{}, nkt - 1);

  float inv = 1.0f / l_run;
  float invq[4];
#pragma unroll
  for (int r = 0; r < 4; ++r) invq[r] = __shfl(inv, (l & 48) | (l4 * 4 + r));
#pragma unroll
  for (int dt = 0; dt < 8; ++dt)
#pragma unroll
    for (int r = 0; r < 4; ++r)
      o_bf[(size_t)(crow + r) * (NH * HD) + h * HD + dt * 16 + l15] =
          f2b(o_acc[dt][r] * invq[r]);
}

extern "C" void kernel_launch(void* const* d_in, const int* in_sizes, int n_in,
                              void* d_out, int out_size, void* d_ws, size_t ws_size,
                              hipStream_t stream) {
  const float* x    = (const float*)d_in[0];
  const float* Wq   = (const float*)d_in[1];
  const float* Wk   = (const float*)d_in[2];
  const float* Wv   = (const float*)d_in[3];
  const float* Wo   = (const float*)d_in[4];
  const float* cost = (const float*)d_in[5];
  const float* sint = (const float*)d_in[6];
  float* out = (float*)d_out;
  char* ws = (char*)d_ws;

  unsigned short* xb     = (unsigned short*)(ws);                 // 16 MB (dead after gemm1)
  unsigned short* wqkv_t = (unsigned short*)(ws + 16777216);      // 48 MB (dead after gemm1)
  unsigned short* wo_t   = (unsigned short*)(ws + 67108864);      // 32 MB
  unsigned short* qkv    = (unsigned short*)(ws + 100663296);     // 24 MB bf16
  signed char*    q_i8   = (signed char*)(ws + 150994944);        // 8 MB (in 16 MB region)
  signed char*    k_i8   = (signed char*)(ws + 167772160);        // 2 MB (in 4 MB region)
  float*          q_ds_t = (float*)(ws + 176160768);              // 256 KB [NH][S]
  float*          k_ds_t = (float*)(ws + 176422912);              // 64 KB  [NKV][S]
  unsigned short* o_bf   = (unsigned short*)(ws + 176488448);     // 16 MB
  unsigned short* v_t    = (unsigned short*)(ws);                 // 4 MB, aliases dead xb

  hipFuncSetAttribute((const void*)k_g128x3,
                      hipFuncAttributeMaxDynamicSharedMemorySize, 81920);
  hipFuncSetAttribute((const void*)k_gksplit,
                      hipFuncAttributeMaxDynamicSharedMemorySize, 65536);

  // merged prep: cvt_x + Wq/Wk/Wv/Wo transposes in one launch
  k_prep<<<dim3(18432), 256, 0, stream>>>(x, Wq, Wk, Wv, Wo, xb, wqkv_t, wo_t);
  // QKV proj: 128x192 tiles -> 512 blocks = 2 blocks/CU; bf16 output
  k_g128x3<<<dim3(512), 512, 81920, stream>>>(xb, wqkv_t, qkv, 2048, 6144, 4096);
  // merged post: RoPE + int8 quant (q,k bytes) + V^T transpose
  k_post<<<dim3(20992), 256, 0, stream>>>(qkv, cost, sint, q_i8, q_ds_t, k_i8, k_ds_t, v_t);
  // attention: i8 QK^T (K=64), 512 blocks x 512 threads, mask-elided tiles
  k_attn<<<dim3(512), 512, 0, stream>>>(q_i8, q_ds_t, k_i8, k_ds_t, v_t, o_bf);
  // out proj: 128x128 tiles, K-split waves -> 512 blocks = 2/CU
  k_gksplit<<<dim3(512), 512, 65536, stream>>>(o_bf, wo_t, out, 2048, 4096, 4096);
}

// Round 19
// 286.519 us; speedup vs baseline: 2.5302x; 1.0070x over previous
//
#include <hip/hip_runtime.h>
#include <hip/hip_bf16.h>

#define S_LEN 2048
#define DMODEL 4096
#define NH 32
#define NKV 8
#define HD 128
#define NQKV 6144
#define VOFF (DMODEL + NKV * HD)  // v-section offset inside a qkv row
// 1/sqrt(128) * log2(e): scores in log2 domain so v_exp_f32 (=2^x) is the exp
#define ATT_SCALE_L2E 0.1275175213528852f

typedef __bf16 bf16x8 __attribute__((ext_vector_type(8)));
typedef __bf16 bf16x4 __attribute__((ext_vector_type(4)));
typedef float f32x4 __attribute__((ext_vector_type(4)));
typedef int i32x4 __attribute__((ext_vector_type(4)));

template <bool B> struct BoolC { static constexpr bool value = B; };

// float -> bf16 bits, round-to-nearest-even
__device__ __forceinline__ unsigned short f2b(float f) {
  union { float f; unsigned u; } a; a.f = f;
  unsigned u = a.u;
  return (unsigned short)((u + 0x7FFFu + ((u >> 16) & 1u)) >> 16);
}
// bf16 bits -> float
__device__ __forceinline__ float b2f(unsigned short u) {
  union { unsigned u; float f; } a; a.u = (unsigned)u << 16; return a.f;
}

__device__ __forceinline__ void gl16(const void* g, void* l) {
  __builtin_amdgcn_global_load_lds(
      (const __attribute__((address_space(1))) unsigned int*)g,
      (__attribute__((address_space(3))) unsigned int*)l, 16, 0, 0);
}

// ============ merged prep: x fp32->bf16 + 4 weight transposes (one launch) ============
__global__ __launch_bounds__(256) void k_prep(const float* __restrict__ x,
                                              const float* __restrict__ Wq,
                                              const float* __restrict__ Wk,
                                              const float* __restrict__ Wv,
                                              const float* __restrict__ Wo,
                                              unsigned short* __restrict__ xb,
                                              unsigned short* __restrict__ wqkv_t,
                                              unsigned short* __restrict__ wo_t) {
  __shared__ float tile[64][65];
  const int id = blockIdx.x;
  if (id >= 10240) {  // ---- cvt_x ----
    int i = (id - 10240) * 256 + threadIdx.x;
    float4 v = ((const float4*)x)[i];
    ushort4 o;
    o.x = f2b(v.x); o.y = f2b(v.y); o.z = f2b(v.z); o.w = f2b(v.w);
    ((ushort4*)xb)[i] = o;
    return;
  }
  const float* W;
  unsigned short* Wt;
  int N, bx, by;
  if (id < 4096)      { W = Wq; Wt = wqkv_t;                         N = 4096; bx = id & 63;          by = id >> 6; }
  else if (id < 5120) { W = Wk; Wt = wqkv_t + (size_t)4096 * 4096;   N = 1024; bx = (id - 4096) & 63; by = (id - 4096) >> 6; }
  else if (id < 6144) { W = Wv; Wt = wqkv_t + (size_t)5120 * 4096;   N = 1024; bx = (id - 5120) & 63; by = (id - 5120) >> 6; }
  else                { W = Wo; Wt = wo_t;                           N = 4096; bx = (id - 6144) & 63; by = (id - 6144) >> 6; }
  const int k0 = bx * 64, n0 = by * 64;
  const int tx = threadIdx.x & 31, ty = threadIdx.x >> 5;
#pragma unroll
  for (int i = 0; i < 8; ++i) {
    int k = ty + i * 8;
    const float* src = W + (size_t)(k0 + k) * N + n0;
    tile[k][tx] = src[tx];
    tile[k][tx + 32] = src[tx + 32];
  }
  __syncthreads();
  int kq = threadIdx.x & 15, nb = threadIdx.x >> 4;
#pragma unroll
  for (int i = 0; i < 4; ++i) {
    int n = nb + i * 16;
    ushort4 o;
    o.x = f2b(tile[kq * 4 + 0][n]);
    o.y = f2b(tile[kq * 4 + 1][n]);
    o.z = f2b(tile[kq * 4 + 2][n]);
    o.w = f2b(tile[kq * 4 + 3][n]);
    *(ushort4*)&Wt[(size_t)(n0 + n) * 4096 + k0 + kq * 4] = o;
  }
}

// ============ merged post-proj: RoPE + INT8 quant (q,k as bytes) + V^T transpose ============
__global__ __launch_bounds__(256) void k_post(const unsigned short* __restrict__ qkv,
                                              const float* __restrict__ cost,
                                              const float* __restrict__ sint,
                                              signed char* __restrict__ q_i8,
                                              float* __restrict__ q_ds_t,
                                              signed char* __restrict__ k_i8,
                                              float* __restrict__ k_ds_t,
                                              unsigned short* __restrict__ v_t) {
  __shared__ unsigned short tile[64][65];
  const int id = blockIdx.x;
  if (id < 20480) {
    int y = id >> 11, s = id & 2047;
    int wv = threadIdx.x >> 6, l = threadIdx.x & 63;
    int hh = y * 4 + wv;
    const unsigned short* row = qkv + (size_t)s * NQKV;
    int off = (hh < NH) ? hh * HD : DMODEL + (hh - NH) * HD;
    float t1 = b2f(row[off + l]), t2 = b2f(row[off + 64 + l]);
    float c1 = cost[s * HD + l],      sn1 = sint[s * HD + l];
    float c2 = cost[s * HD + 64 + l], sn2 = sint[s * HD + 64 + l];
    float o1 = t1 * c1 - t2 * sn1;
    float o2 = t2 * c2 + t1 * sn2;
    float amax = fmaxf(fabsf(o1), fabsf(o2));
#pragma unroll
    for (int m = 1; m < 64; m <<= 1) amax = fmaxf(amax, __shfl_xor(amax, m));
    amax = fmaxf(amax, 1e-5f);
    float scale = 127.0f / amax;
    float dscale = amax * (1.0f / 127.0f);
    float v1 = fminf(fmaxf(rintf(o1 * scale), -128.f), 127.f);
    float v2 = fminf(fmaxf(rintf(o2 * scale), -128.f), 127.f);
    if (hh < NH) {
      signed char* dst = q_i8 + ((size_t)s * NH + hh) * HD;
      dst[l] = (signed char)v1; dst[l + 64] = (signed char)v2;
      if (l == 0) q_ds_t[(size_t)hh * S_LEN + s] = dscale;
    } else {
      int kh = hh - NH;
      signed char* dst = k_i8 + ((size_t)s * NKV + kh) * HD;
      dst[l] = (signed char)v1; dst[l + 64] = (signed char)v2;
      if (l == 0) k_ds_t[(size_t)kh * S_LEN + s] = dscale;
    }
    return;
  }
  int vid = id - 20480;
  int s0 = (vid & 31) * 64, d0 = ((vid >> 5) & 1) * 64, kvh = vid >> 6;
  int tx = threadIdx.x & 63, ty = threadIdx.x >> 6;
#pragma unroll
  for (int i = 0; i < 16; ++i) {
    int s = ty + i * 4;
    tile[s][tx] = qkv[(size_t)(s0 + s) * NQKV + VOFF + kvh * HD + d0 + tx];
  }
  __syncthreads();
#pragma unroll
  for (int i = 0; i < 16; ++i) {
    int d = ty + i * 4;
    v_t[((size_t)kvh * HD + d0 + d) * S_LEN + s0 + tx] = tile[tx][d];
  }
}

// ====== 256 x 192 GEMM, 8-PHASE quadrant schedule (T3+T4), 1 block/CU — QKV proj ======
// 512 thr = 8 waves (4M x 2N); per-wave output 64x96 = acc[2][2][2][3] (96 VGPR; cap 256
// at 2 waves/SIMD). LDS 112 KB: A 2x(2x16KB halves) + B 2x24KB -> 1 block/CU; grid
// 8x32 = 256 = exact fill. Quadrant phases (ah,bh): (0,0)(0,1)(1,1)(1,0); operands held
// across quadrants -> 10 ds_reads / 48 MFMA per wave per K-tile (ratio 0.21). Stage
// placement race-free per round-4-verified pattern; counted boundary vmcnt(4) keeps
// stA(t+2) in flight (never drains to 0 mid-loop). G4 3-bit swizzle (rows == l15 mod 8).
__global__ __launch_bounds__(512, 2) void k_g256x192(const unsigned short* __restrict__ A,
                                                     const unsigned short* __restrict__ B,
                                                     unsigned short* __restrict__ C,
                                                     int M, int N, int K) {
  extern __shared__ __align__(16) unsigned short smem[];
  char* Sc = (char*)smem;
  const int tid = threadIdx.x;
  const int wvid = tid >> 6, l = tid & 63;
  const int wm = wvid >> 1, wn = wvid & 1;   // 4M x 2N
  const int l15 = l & 15, l4 = l >> 4;

  const int cpx = gridDim.x >> 3;            // 32 (grid 256)
  const int swz = (blockIdx.x & 7) * cpx + (blockIdx.x >> 3);
  const int mtiles = M >> 8;                 // 8
  const int m0 = (swz % mtiles) * 256;
  const int n0 = (swz / mtiles) * 192;

  const int NT = K >> 6;

  const int rsw = (l15 & 7) << 4;
  const int a_base = (wm * 32 + l15) * 128;  // + fm*2048 + c{0,1}, within a 16KB half
  const int b_base = (wn * 48 + l15) * 128;  // + bh*12288 + fn*2048 + c{0,1}
  const int c0 = (l4 * 16) ^ rsw;
  const int c1 = (64 + l4 * 16) ^ rsw;

  const int srow = l >> 3;
  const int st_k8 = (l & 7) ^ (srow & 7);

  auto stA = [&](int tt, int h) {  // one 16 KB half: 2 gl16/thread
    if (tt >= NT) return;
    const unsigned short* g = A + (size_t)(m0 + h * 128 + wvid * 8 + srow) * K + tt * 64 + st_k8 * 8;
    char* lb = Sc + (tt & 1) * 32768 + h * 16384 + wvid * 1024;
#pragma unroll
    for (int j = 0; j < 2; ++j)
      gl16(g + (size_t)(j * 64) * K, lb + j * 8192);
  };
  auto stB = [&](int tt) {  // 24 KB: 3 gl16/thread
    if (tt >= NT) return;
    const unsigned short* g = B + (size_t)(n0 + wvid * 8 + srow) * K + tt * 64 + st_k8 * 8;
    char* lb = Sc + 65536 + (tt & 1) * 24576 + wvid * 1024;
#pragma unroll
    for (int j = 0; j < 3; ++j)
      gl16(g + (size_t)(j * 64) * K, lb + j * 8192);
  };

  f32x4 acc[2][2][2][3] = {};  // [ah][fm][bh][fn]

  // prologue: t0 fully, t1's A halves; vmcnt(4) leaves stA(1,*) in flight
  stA(0, 0); stA(0, 1); stB(0);
  stA(1, 0); stA(1, 1);
  if (NT > 1) asm volatile("s_waitcnt vmcnt(4)" ::: "memory");
  else        asm volatile("s_waitcnt vmcnt(0)" ::: "memory");
  __builtin_amdgcn_s_barrier();

  for (int t = 0; t < NT; ++t) {
    const char* Ab = Sc + (t & 1) * 32768;
    const char* Bb = Sc + 65536 + (t & 1) * 24576;
    bf16x8 a[2][2], b0[3][2], b1[3][2];

    // ===== ph1 (Ah0 x Bh0): read a(4) + b0(6); stage B(t+1) -> other buf =====
#pragma unroll
    for (int fm = 0; fm < 2; ++fm) {
      a[fm][0] = *(const bf16x8*)(Ab + a_base + fm * 2048 + c0);
      a[fm][1] = *(const bf16x8*)(Ab + a_base + fm * 2048 + c1);
    }
#pragma unroll
    for (int fn = 0; fn < 3; ++fn) {
      b0[fn][0] = *(const bf16x8*)(Bb + b_base + fn * 2048 + c0);
      b0[fn][1] = *(const bf16x8*)(Bb + b_base + fn * 2048 + c1);
    }
    stB(t + 1);
    __builtin_amdgcn_s_barrier();
    __builtin_amdgcn_s_setprio(1);
#pragma unroll
    for (int fm = 0; fm < 2; ++fm)
#pragma unroll
      for (int fn = 0; fn < 3; ++fn)
#pragma unroll
        for (int ks = 0; ks < 2; ++ks)
          acc[0][fm][0][fn] = __builtin_amdgcn_mfma_f32_16x16x32_bf16(a[fm][ks], b0[fn][ks], acc[0][fm][0][fn], 0, 0, 0);
    __builtin_amdgcn_s_setprio(0);
    __builtin_amdgcn_s_barrier();

    // ===== ph2 (Ah0 x Bh1): read b1(6); stage A(t+2,h0) — Ah0(t) reads done in ph1 =====
#pragma unroll
    for (int fn = 0; fn < 3; ++fn) {
      b1[fn][0] = *(const bf16x8*)(Bb + 12288 + b_base + fn * 2048 + c0);
      b1[fn][1] = *(const bf16x8*)(Bb + 12288 + b_base + fn * 2048 + c1);
    }
    stA(t + 2, 0);
    __builtin_amdgcn_s_barrier();
    __builtin_amdgcn_s_setprio(1);
#pragma unroll
    for (int fm = 0; fm < 2; ++fm)
#pragma unroll
      for (int fn = 0; fn < 3; ++fn)
#pragma unroll
        for (int ks = 0; ks < 2; ++ks)
          acc[0][fm][1][fn] = __builtin_amdgcn_mfma_f32_16x16x32_bf16(a[fm][ks], b1[fn][ks], acc[0][fm][1][fn], 0, 0, 0);
    __builtin_amdgcn_s_setprio(0);
    __builtin_amdgcn_s_barrier();

    // ===== ph3 (Ah1 x Bh1): read a <- Ah1(4); b1 held =====
#pragma unroll
    for (int fm = 0; fm < 2; ++fm) {
      a[fm][0] = *(const bf16x8*)(Ab + 16384 + a_base + fm * 2048 + c0);
      a[fm][1] = *(const bf16x8*)(Ab + 16384 + a_base + fm * 2048 + c1);
    }
    __builtin_amdgcn_s_barrier();
    __builtin_amdgcn_s_setprio(1);
#pragma unroll
    for (int fm = 0; fm < 2; ++fm)
#pragma unroll
      for (int fn = 0; fn < 3; ++fn)
#pragma unroll
        for (int ks = 0; ks < 2; ++ks)
          acc[1][fm][1][fn] = __builtin_amdgcn_mfma_f32_16x16x32_bf16(a[fm][ks], b1[fn][ks], acc[1][fm][1][fn], 0, 0, 0);
    __builtin_amdgcn_s_setprio(0);
    __builtin_amdgcn_s_barrier();

    // ===== ph4 (Ah1 x Bh0): a,b0 held; stage A(t+2,h1) — Ah1(t) reads done in ph3 =====
    stA(t + 2, 1);
    __builtin_amdgcn_s_barrier();
    __builtin_amdgcn_s_setprio(1);
#pragma unroll
    for (int fm = 0; fm < 2; ++fm)
#pragma unroll
      for (int fn = 0; fn < 3; ++fn)
#pragma unroll
        for (int ks = 0; ks < 2; ++ks)
          acc[1][fm][0][fn] = __builtin_amdgcn_mfma_f32_16x16x32_bf16(a[fm][ks], b0[fn][ks], acc[1][fm][0][fn], 0, 0, 0);
    __builtin_amdgcn_s_setprio(0);
    if (t + 1 < NT) {
      if (t + 1 == NT - 1) asm volatile("s_waitcnt vmcnt(0)" ::: "memory");
      else                 asm volatile("s_waitcnt vmcnt(4)" ::: "memory");
    }
    __builtin_amdgcn_s_barrier();
  }

  // ---- epilogue: bf16 C write ----
#pragma unroll
  for (int ah = 0; ah < 2; ++ah)
#pragma unroll
    for (int fm = 0; fm < 2; ++fm) {
      int row0 = m0 + ah * 128 + wm * 32 + fm * 16 + l4 * 4;
#pragma unroll
      for (int bh = 0; bh < 2; ++bh)
#pragma unroll
        for (int fn = 0; fn < 3; ++fn) {
          int col = n0 + bh * 96 + wn * 48 + fn * 16 + l15;
#pragma unroll
          for (int r = 0; r < 4; ++r)
            C[(size_t)(row0 + r) * N + col] = f2b(acc[ah][fm][bh][fn][r]);
        }
    }
}

// ===== 128 x 128 GEMM, K-SPLIT waves, per-wave 64x64 — out proj (PROVEN) =====
__global__ __launch_bounds__(512, 4) void k_gksplit(const unsigned short* __restrict__ A,
                                                    const unsigned short* __restrict__ B,
                                                    float* __restrict__ C,
                                                    int M, int N, int K) {
  extern __shared__ __align__(16) unsigned short smem[];
  char* Sc = (char*)smem;
  const int tid = threadIdx.x;
  const int wvid = tid >> 6, l = tid & 63;
  const int wm = wvid & 1, wn = (wvid >> 1) & 1, wk = wvid >> 2;
  const int l15 = l & 15, l4 = l >> 4;

  const int cpx = gridDim.x >> 3;
  const int swz = (blockIdx.x & 7) * cpx + (blockIdx.x >> 3);
  const int mtiles = M >> 7;
  const int m0 = (swz % mtiles) * 128;
  const int n0 = (swz / mtiles) * 128;

  const int NT = K >> 6;

  const int rsw = (l15 & 7) << 4;
  const int a_base = (wm * 64 + l15) * 128;
  const int b_base = (wn * 64 + l15) * 128;
  const int ck = (wk * 64 + l4 * 16) ^ rsw;

  const int srow = l >> 3;
  const int st_k8 = (l & 7) ^ (srow & 7);

  auto stA = [&](int tt) {
    if (tt >= NT) return;
    const unsigned short* g = A + (size_t)(m0 + wvid * 8 + srow) * K + tt * 64 + st_k8 * 8;
    char* lb = Sc + (tt & 1) * 16384 + wvid * 1024;
#pragma unroll
    for (int j = 0; j < 2; ++j)
      gl16(g + (size_t)(j * 64) * K, lb + j * 8192);
  };
  auto stB = [&](int tt) {
    if (tt >= NT) return;
    const unsigned short* g = B + (size_t)(n0 + wvid * 8 + srow) * K + tt * 64 + st_k8 * 8;
    char* lb = Sc + 32768 + (tt & 1) * 16384 + wvid * 1024;
#pragma unroll
    for (int j = 0; j < 2; ++j)
      gl16(g + (size_t)(j * 64) * K, lb + j * 8192);
  };

  f32x4 acc[4][4] = {};

  stA(0); stB(0); stA(1);
  if (NT > 1) asm volatile("s_waitcnt vmcnt(2)" ::: "memory");
  else        asm volatile("s_waitcnt vmcnt(0)" ::: "memory");
  __builtin_amdgcn_s_barrier();

  for (int t = 0; t < NT; ++t) {
    const char* Ab = Sc + (t & 1) * 16384;
    const char* Bb = Sc + 32768 + (t & 1) * 16384;
    stB(t + 1);
    bf16x8 a[4], b[4];
#pragma unroll
    for (int fm = 0; fm < 4; ++fm) a[fm] = *(const bf16x8*)(Ab + a_base + fm * 2048 + ck);
#pragma unroll
    for (int fn = 0; fn < 4; ++fn) b[fn] = *(const bf16x8*)(Bb + b_base + fn * 2048 + ck);
    __builtin_amdgcn_s_setprio(1);
#pragma unroll
    for (int fm = 0; fm < 4; ++fm)
#pragma unroll
      for (int fn = 0; fn < 4; ++fn)
        acc[fm][fn] = __builtin_amdgcn_mfma_f32_16x16x32_bf16(a[fm], b[fn], acc[fm][fn], 0, 0, 0);
    __builtin_amdgcn_s_setprio(0);
    __builtin_amdgcn_s_barrier();
    stA(t + 2);
    if (t + 1 < NT) {
      if (t + 1 == NT - 1) asm volatile("s_waitcnt vmcnt(0)" ::: "memory");
      else                 asm volatile("s_waitcnt vmcnt(2)" ::: "memory");
      __builtin_amdgcn_s_barrier();
    }
  }

  char* xch = Sc + (wm * 2 + wn) * 16384;
  if (wk == 1) {
#pragma unroll
    for (int fm = 0; fm < 4; ++fm)
#pragma unroll
      for (int fn = 0; fn < 4; ++fn)
        *(f32x4*)(xch + (fm * 4 + fn) * 1024 + l * 16) = acc[fm][fn];
  }
  __syncthreads();
  if (wk == 0) {
#pragma unroll
    for (int fm = 0; fm < 4; ++fm) {
      int row0 = m0 + wm * 64 + fm * 16 + l4 * 4;
#pragma unroll
      for (int fn = 0; fn < 4; ++fn) {
        f32x4 o = *(const f32x4*)(xch + (fm * 4 + fn) * 1024 + l * 16);
        int col = n0 + wn * 64 + fn * 16 + l15;
#pragma unroll
        for (int r = 0; r < 4; ++r)
          C[(size_t)(row0 + r) * N + col] = acc[fm][fn][r] + o[r];
      }
    }
  }
}

// ------------- causal GQA flash attention: i8 MFMA QK^T (K=64), bf16 PV (PROVEN) -------------
__global__ __launch_bounds__(512, 4) void k_attn(const signed char* __restrict__ q_i8,
                                                 const float* __restrict__ q_ds_t,
                                                 const signed char* __restrict__ k_i8,
                                                 const float* __restrict__ k_ds_t,
                                                 const unsigned short* __restrict__ v_t,
                                                 unsigned short* __restrict__ o_bf) {
  __shared__ __align__(16) signed char K_lds[2][8192];
  __shared__ __align__(16) unsigned short V_lds[2][8192];
  __shared__ __align__(16) unsigned short P_lds[8][1024];

  const int bid = blockIdx.x;
  const int kvh = bid & 7;
  const int qt = 63 - (bid >> 3);
  const int tid = threadIdx.x, wv = tid >> 6, l = tid & 63;
  const int l15 = l & 15, l4 = l >> 4;
  const int h = kvh * 4 + (wv & 3);
  const int rh = wv >> 2;

  auto stage = [&](int b, int kt) {
    {
      int key = tid >> 3, g = tid & 7;
      int colb = (g * 16) ^ ((key & 7) << 4);
      const signed char* src = k_i8 + ((size_t)(kt * 64 + key) * NKV + kvh) * HD + colb;
      gl16(src, &K_lds[b][tid * 16]);
    }
    const unsigned short* vB = v_t + (size_t)kvh * HD * S_LEN + (size_t)kt * 64;
#pragma unroll
    for (int j = 0; j < 2; ++j) {
      int wi = j * 8 + wv;
      int slot = wi * 64 + l;
      int d = slot >> 3;
      int ckb = ((slot & 7) * 16) ^ ((d & 7) << 4);
      gl16(vB + (size_t)d * S_LEN + (ckb >> 1), &V_lds[b][wi * 512]);
    }
  };

  const int qrow_lo = qt * 32 + rh * 16;
  const int qg = qrow_lo + l15;
  const int crow = qrow_lo + l4 * 4;

  i32x4 qf[2];
  {
    const signed char* qp = q_i8 + ((size_t)qg * NH + h) * HD + l4 * 16;
    qf[0] = *(const i32x4*)(qp);
    qf[1] = *(const i32x4*)(qp + 64);
  }
  const float qsS = ATT_SCALE_L2E * q_ds_t[(size_t)h * S_LEN + qg];

  float m_run = -3.0e38f, l_run = 0.f;
  f32x4 o_acc[8] = {};

  const int nkt = (qt >> 1) + 1;
  stage(0, 0);
  __syncthreads();

  const int psw = (l15 & 7) << 4;

  auto tileBody = [&](auto mc, int kt) {
    constexpr bool MASKED = decltype(mc)::value;
    const int cur = kt & 1;
    f32x4 ksd[4];
    {
      const f32x4* kdp = (const f32x4*)(k_ds_t + (size_t)kvh * S_LEN + kt * 64 + l4 * 4);
#pragma unroll
      for (int nt = 0; nt < 4; ++nt) ksd[nt] = kdp[nt * 4];
    }
    if (kt + 1 < nkt) stage(cur ^ 1, kt + 1);

    i32x4 sacc[4] = {};
#pragma unroll
    for (int nt = 0; nt < 4; ++nt) {
      int key = nt * 16 + l15;
#pragma unroll
      for (int kd = 0; kd < 2; ++kd) {
        int byte = key * 128 + kd * 64 + l4 * 16;
        byte ^= (key & 7) << 4;
        i32x4 kf = *(const i32x4*)(&K_lds[cur][0] + byte);
        sacc[nt] = __builtin_amdgcn_mfma_i32_16x16x64_i8(kf, qf[kd], sacc[nt], 0, 0, 0);
      }
    }

    float p[4][4];
    float tmax = -3.0e38f;
#pragma unroll
    for (int nt = 0; nt < 4; ++nt) {
#pragma unroll
      for (int r = 0; r < 4; ++r) {
        float sc = (float)sacc[nt][r] * (qsS * ksd[nt][r]);
        if constexpr (MASKED) {
          int keyg = kt * 64 + nt * 16 + l4 * 4 + r;
          sc = (keyg <= qg) ? sc : -3.0e38f;
        }
        p[nt][r] = sc;
        tmax = fmaxf(tmax, sc);
      }
    }
    tmax = fmaxf(tmax, __shfl_xor(tmax, 16));
    tmax = fmaxf(tmax, __shfl_xor(tmax, 32));

    float nm = fmaxf(m_run, tmax);
    bool need = tmax > m_run + 11.0f;
    if (__ballot(need)) {
      float corr = __builtin_amdgcn_exp2f(m_run - nm);
      m_run = nm;
      l_run *= corr;
      float cq[4];
#pragma unroll
      for (int r = 0; r < 4; ++r) cq[r] = __shfl(corr, (l & 48) | (l4 * 4 + r));
#pragma unroll
      for (int dt = 0; dt < 8; ++dt)
#pragma unroll
        for (int r = 0; r < 4; ++r) o_acc[dt][r] *= cq[r];
    }

    float psum = 0.f;
#pragma unroll
    for (int nt = 0; nt < 4; ++nt)
#pragma unroll
      for (int r = 0; r < 4; ++r) {
        float e = __builtin_amdgcn_exp2f(p[nt][r] - m_run);
        p[nt][r] = e;
        psum += e;
      }
    psum += __shfl_xor(psum, 16);
    psum += __shfl_xor(psum, 32);
    l_run += psum;

#pragma unroll
    for (int nt = 0; nt < 4; ++nt) {
      bf16x4 pk;
      pk[0] = (__bf16)p[nt][0]; pk[1] = (__bf16)p[nt][1];
      pk[2] = (__bf16)p[nt][2]; pk[3] = (__bf16)p[nt][3];
      int bw = l15 * 128 + ((nt * 32 + l4 * 8) ^ psw);
      *(bf16x4*)((char*)&P_lds[wv][0] + bw) = pk;
    }
    bf16x8 pa[2];
#pragma unroll
    for (int kc = 0; kc < 2; ++kc) {
      int br = l15 * 128 + ((kc * 64 + l4 * 16) ^ psw);
      pa[kc] = *(const bf16x8*)((const char*)&P_lds[wv][0] + br);
    }

#pragma unroll
    for (int dt = 0; dt < 8; ++dt) {
      int d = dt * 16 + l15;
      int swzv = (d & 7) << 4;
#pragma unroll
      for (int kc = 0; kc < 2; ++kc) {
        int byte = d * 128 + ((kc * 64 + l4 * 16) ^ swzv);
        bf16x8 vb = *(const bf16x8*)((const char*)&V_lds[cur][0] + byte);
        o_acc[dt] = __builtin_amdgcn_mfma_f32_16x16x32_bf16(pa[kc], vb, o_acc[dt], 0, 0, 0);
      }
    }
    __syncthreads();
  };

  for (int kt = 0; kt + 1 < nkt; ++kt) tileBody(BoolC<false>{}, kt);
  tileBody(BoolC<true>{}, nkt - 1);

  float inv = 1.0f / l_run;
  float invq[4];
#pragma unroll
  for (int r = 0; r < 4; ++r) invq[r] = __shfl(inv, (l & 48) | (l4 * 4 + r));
#pragma unroll
  for (int dt = 0; dt < 8; ++dt)
#pragma unroll
    for (int r = 0; r < 4; ++r)
      o_bf[(size_t)(crow + r) * (NH * HD) + h * HD + dt * 16 + l15] =
          f2b(o_acc[dt][r] * invq[r]);
}

extern "C" void kernel_launch(void* const* d_in, const int* in_sizes, int n_in,
                              void* d_out, int out_size, void* d_ws, size_t ws_size,
                              hipStream_t stream) {
  const float* x    = (const float*)d_in[0];
  const float* Wq   = (const float*)d_in[1];
  const float* Wk   = (const float*)d_in[2];
  const float* Wv   = (const float*)d_in[3];
  const float* Wo   = (const float*)d_in[4];
  const float* cost = (const float*)d_in[5];
  const float* sint = (const float*)d_in[6];
  float* out = (float*)d_out;
  char* ws = (char*)d_ws;

  unsigned short* xb     = (unsigned short*)(ws);                 // 16 MB (dead after gemm1)
  unsigned short* wqkv_t = (unsigned short*)(ws + 16777216);      // 48 MB (dead after gemm1)
  unsigned short* wo_t   = (unsigned short*)(ws + 67108864);      // 32 MB
  unsigned short* qkv    = (unsigned short*)(ws + 100663296);     // 24 MB bf16
  signed char*    q_i8   = (signed char*)(ws + 150994944);        // 8 MB
  signed char*    k_i8   = (signed char*)(ws + 167772160);        // 2 MB
  float*          q_ds_t = (float*)(ws + 176160768);              // 256 KB [NH][S]
  float*          k_ds_t = (float*)(ws + 176422912);              // 64 KB  [NKV][S]
  unsigned short* o_bf   = (unsigned short*)(ws + 176488448);     // 16 MB
  unsigned short* v_t    = (unsigned short*)(ws);                 // 4 MB, aliases dead xb

  hipFuncSetAttribute((const void*)k_g256x192,
                      hipFuncAttributeMaxDynamicSharedMemorySize, 114688);
  hipFuncSetAttribute((const void*)k_gksplit,
                      hipFuncAttributeMaxDynamicSharedMemorySize, 65536);

  // merged prep: cvt_x + Wq/Wk/Wv/Wo transposes in one launch
  k_prep<<<dim3(18432), 256, 0, stream>>>(x, Wq, Wk, Wv, Wo, xb, wqkv_t, wo_t);
  // QKV proj: 256x192 tiles, 8-phase schedule -> 256 blocks = exact 1/CU; bf16 output
  k_g256x192<<<dim3(256), 512, 114688, stream>>>(xb, wqkv_t, qkv, 2048, 6144, 4096);
  // merged post: RoPE + int8 quant (q,k bytes) + V^T transpose
  k_post<<<dim3(20992), 256, 0, stream>>>(qkv, cost, sint, q_i8, q_ds_t, k_i8, k_ds_t, v_t);
  // attention: i8 QK^T (K=64), 512 blocks x 512 threads, mask-elided tiles
  k_attn<<<dim3(512), 512, 0, stream>>>(q_i8, q_ds_t, k_i8, k_ds_t, v_t, o_bf);
  // out proj: 128x128 tiles, K-split waves -> 512 blocks = 2/CU
  k_gksplit<<<dim3(512), 512, 65536, stream>>>(o_bf, wo_t, out, 2048, 4096, 4096);
}

// Round 20
// 285.267 us; speedup vs baseline: 2.5413x; 1.0044x over previous
//
#include <hip/hip_runtime.h>
#include <hip/hip_bf16.h>

#define S_LEN 2048
#define DMODEL 4096
#define NH 32
#define NKV 8
#define HD 128
#define NQKV 6144
#define VOFF (DMODEL + NKV * HD)  // v-section offset inside a qkv row
// 1/sqrt(128) * log2(e): scores in log2 domain so v_exp_f32 (=2^x) is the exp
#define ATT_SCALE_L2E 0.1275175213528852f

typedef __bf16 bf16x8 __attribute__((ext_vector_type(8)));
typedef __bf16 bf16x4 __attribute__((ext_vector_type(4)));
typedef float f32x4 __attribute__((ext_vector_type(4)));
typedef int i32x4 __attribute__((ext_vector_type(4)));

template <bool B> struct BoolC { static constexpr bool value = B; };

// float -> bf16 bits, round-to-nearest-even
__device__ __forceinline__ unsigned short f2b(float f) {
  union { float f; unsigned u; } a; a.f = f;
  unsigned u = a.u;
  return (unsigned short)((u + 0x7FFFu + ((u >> 16) & 1u)) >> 16);
}
// bf16 bits -> float
__device__ __forceinline__ float b2f(unsigned short u) {
  union { unsigned u; float f; } a; a.u = (unsigned)u << 16; return a.f;
}

__device__ __forceinline__ void gl16(const void* g, void* l) {
  __builtin_amdgcn_global_load_lds(
      (const __attribute__((address_space(1))) unsigned int*)g,
      (__attribute__((address_space(3))) unsigned int*)l, 16, 0, 0);
}

// ============ merged prep: x fp32->bf16 + 4 weight transposes (one launch) ============
__global__ __launch_bounds__(256) void k_prep(const float* __restrict__ x,
                                              const float* __restrict__ Wq,
                                              const float* __restrict__ Wk,
                                              const float* __restrict__ Wv,
                                              const float* __restrict__ Wo,
                                              unsigned short* __restrict__ xb,
                                              unsigned short* __restrict__ wqkv_t,
                                              unsigned short* __restrict__ wo_t) {
  __shared__ float tile[64][65];
  const int id = blockIdx.x;
  if (id >= 10240) {  // ---- cvt_x ----
    int i = (id - 10240) * 256 + threadIdx.x;
    float4 v = ((const float4*)x)[i];
    ushort4 o;
    o.x = f2b(v.x); o.y = f2b(v.y); o.z = f2b(v.z); o.w = f2b(v.w);
    ((ushort4*)xb)[i] = o;
    return;
  }
  const float* W;
  unsigned short* Wt;
  int N, bx, by;
  if (id < 4096)      { W = Wq; Wt = wqkv_t;                         N = 4096; bx = id & 63;          by = id >> 6; }
  else if (id < 5120) { W = Wk; Wt = wqkv_t + (size_t)4096 * 4096;   N = 1024; bx = (id - 4096) & 63; by = (id - 4096) >> 6; }
  else if (id < 6144) { W = Wv; Wt = wqkv_t + (size_t)5120 * 4096;   N = 1024; bx = (id - 5120) & 63; by = (id - 5120) >> 6; }
  else                { W = Wo; Wt = wo_t;                           N = 4096; bx = (id - 6144) & 63; by = (id - 6144) >> 6; }
  const int k0 = bx * 64, n0 = by * 64;
  const int tx = threadIdx.x & 31, ty = threadIdx.x >> 5;
#pragma unroll
  for (int i = 0; i < 8; ++i) {
    int k = ty + i * 8;
    const float* src = W + (size_t)(k0 + k) * N + n0;
    tile[k][tx] = src[tx];
    tile[k][tx + 32] = src[tx + 32];
  }
  __syncthreads();
  int kq = threadIdx.x & 15, nb = threadIdx.x >> 4;
#pragma unroll
  for (int i = 0; i < 4; ++i) {
    int n = nb + i * 16;
    ushort4 o;
    o.x = f2b(tile[kq * 4 + 0][n]);
    o.y = f2b(tile[kq * 4 + 1][n]);
    o.z = f2b(tile[kq * 4 + 2][n]);
    o.w = f2b(tile[kq * 4 + 3][n]);
    *(ushort4*)&Wt[(size_t)(n0 + n) * 4096 + k0 + kq * 4] = o;
  }
}

// ============ merged post-proj: RoPE + INT8 quant (q,k as bytes) + V^T transpose ============
__global__ __launch_bounds__(256) void k_post(const unsigned short* __restrict__ qkv,
                                              const float* __restrict__ cost,
                                              const float* __restrict__ sint,
                                              signed char* __restrict__ q_i8,
                                              float* __restrict__ q_ds_t,
                                              signed char* __restrict__ k_i8,
                                              float* __restrict__ k_ds_t,
                                              unsigned short* __restrict__ v_t) {
  __shared__ unsigned short tile[64][65];
  const int id = blockIdx.x;
  if (id < 20480) {
    int y = id >> 11, s = id & 2047;
    int wv = threadIdx.x >> 6, l = threadIdx.x & 63;
    int hh = y * 4 + wv;
    const unsigned short* row = qkv + (size_t)s * NQKV;
    int off = (hh < NH) ? hh * HD : DMODEL + (hh - NH) * HD;
    float t1 = b2f(row[off + l]), t2 = b2f(row[off + 64 + l]);
    float c1 = cost[s * HD + l],      sn1 = sint[s * HD + l];
    float c2 = cost[s * HD + 64 + l], sn2 = sint[s * HD + 64 + l];
    float o1 = t1 * c1 - t2 * sn1;
    float o2 = t2 * c2 + t1 * sn2;
    float amax = fmaxf(fabsf(o1), fabsf(o2));
#pragma unroll
    for (int m = 1; m < 64; m <<= 1) amax = fmaxf(amax, __shfl_xor(amax, m));
    amax = fmaxf(amax, 1e-5f);
    float scale = 127.0f / amax;
    float dscale = amax * (1.0f / 127.0f);
    float v1 = fminf(fmaxf(rintf(o1 * scale), -128.f), 127.f);
    float v2 = fminf(fmaxf(rintf(o2 * scale), -128.f), 127.f);
    if (hh < NH) {
      signed char* dst = q_i8 + ((size_t)s * NH + hh) * HD;
      dst[l] = (signed char)v1; dst[l + 64] = (signed char)v2;
      if (l == 0) q_ds_t[(size_t)hh * S_LEN + s] = dscale;
    } else {
      int kh = hh - NH;
      signed char* dst = k_i8 + ((size_t)s * NKV + kh) * HD;
      dst[l] = (signed char)v1; dst[l + 64] = (signed char)v2;
      if (l == 0) k_ds_t[(size_t)kh * S_LEN + s] = dscale;
    }
    return;
  }
  int vid = id - 20480;
  int s0 = (vid & 31) * 64, d0 = ((vid >> 5) & 1) * 64, kvh = vid >> 6;
  int tx = threadIdx.x & 63, ty = threadIdx.x >> 6;
#pragma unroll
  for (int i = 0; i < 16; ++i) {
    int s = ty + i * 4;
    tile[s][tx] = qkv[(size_t)(s0 + s) * NQKV + VOFF + kvh * HD + d0 + tx];
  }
  __syncthreads();
#pragma unroll
  for (int i = 0; i < 16; ++i) {
    int d = ty + i * 4;
    v_t[((size_t)kvh * HD + d0 + d) * S_LEN + s0 + tx] = tile[tx][d];
  }
}

// ====== 256 x 192 GEMM, quadrant schedule, MINIMAL barriers (3/K-tile) — QKV proj ======
// 512 thr = 8 waves (4M x 2N); per-wave output 64x96 = acc[2][2][2][3]. LDS 112 KB ->
// 1 block/CU; grid 256 = exact fill. Quadrants (ah,bh): (0,0)(0,1)(1,1)(1,0); operands
// held across quadrants (10 ds_reads / 48 MFMA / wave / K-tile). Only hazard-bearing
// barriers kept: post-ph1 (gates stA(t+2,0) overwriting Ah0), post-ph3 (gates
// stA(t+2,1) overwriting Ah1), boundary (buffer swap; counted vmcnt(4) keeps the 4
// stA(t+2) loads in flight, vmcnt(0) when t+2 past end). Pre-MFMA barriers removed:
// MFMA->ds_read deps are wave-local (compiler lgkmcnt), enabling cross-phase pipelining.
__global__ __launch_bounds__(512, 2) void k_g256x192(const unsigned short* __restrict__ A,
                                                     const unsigned short* __restrict__ B,
                                                     unsigned short* __restrict__ C,
                                                     int M, int N, int K) {
  extern __shared__ __align__(16) unsigned short smem[];
  char* Sc = (char*)smem;
  const int tid = threadIdx.x;
  const int wvid = tid >> 6, l = tid & 63;
  const int wm = wvid >> 1, wn = wvid & 1;   // 4M x 2N
  const int l15 = l & 15, l4 = l >> 4;

  const int cpx = gridDim.x >> 3;            // 32 (grid 256)
  const int swz = (blockIdx.x & 7) * cpx + (blockIdx.x >> 3);
  const int mtiles = M >> 8;                 // 8
  const int m0 = (swz % mtiles) * 256;
  const int n0 = (swz / mtiles) * 192;

  const int NT = K >> 6;

  const int rsw = (l15 & 7) << 4;
  const int a_base = (wm * 32 + l15) * 128;  // + fm*2048 + c{0,1}, within a 16KB half
  const int b_base = (wn * 48 + l15) * 128;  // + bh*12288 + fn*2048 + c{0,1}
  const int c0 = (l4 * 16) ^ rsw;
  const int c1 = (64 + l4 * 16) ^ rsw;

  const int srow = l >> 3;
  const int st_k8 = (l & 7) ^ (srow & 7);

  auto stA = [&](int tt, int h) {  // one 16 KB half: 2 gl16/thread
    if (tt >= NT) return;
    const unsigned short* g = A + (size_t)(m0 + h * 128 + wvid * 8 + srow) * K + tt * 64 + st_k8 * 8;
    char* lb = Sc + (tt & 1) * 32768 + h * 16384 + wvid * 1024;
#pragma unroll
    for (int j = 0; j < 2; ++j)
      gl16(g + (size_t)(j * 64) * K, lb + j * 8192);
  };
  auto stB = [&](int tt) {  // 24 KB: 3 gl16/thread
    if (tt >= NT) return;
    const unsigned short* g = B + (size_t)(n0 + wvid * 8 + srow) * K + tt * 64 + st_k8 * 8;
    char* lb = Sc + 65536 + (tt & 1) * 24576 + wvid * 1024;
#pragma unroll
    for (int j = 0; j < 3; ++j)
      gl16(g + (size_t)(j * 64) * K, lb + j * 8192);
  };

  f32x4 acc[2][2][2][3] = {};  // [ah][fm][bh][fn]

  // prologue: t0 fully, t1's A halves; vmcnt(4) leaves stA(1,*) in flight
  stA(0, 0); stA(0, 1); stB(0);
  stA(1, 0); stA(1, 1);
  if (NT > 1) asm volatile("s_waitcnt vmcnt(4)" ::: "memory");
  else        asm volatile("s_waitcnt vmcnt(0)" ::: "memory");
  __builtin_amdgcn_s_barrier();

  for (int t = 0; t < NT; ++t) {
    const char* Ab = Sc + (t & 1) * 32768;
    const char* Bb = Sc + 65536 + (t & 1) * 24576;
    bf16x8 a[2][2], b0[3][2], b1[3][2];

    // ===== ph1 (Ah0 x Bh0): stage B(t+1) -> other buf; read a(4) + b0(6); MFMA =====
    stB(t + 1);
#pragma unroll
    for (int fm = 0; fm < 2; ++fm) {
      a[fm][0] = *(const bf16x8*)(Ab + a_base + fm * 2048 + c0);
      a[fm][1] = *(const bf16x8*)(Ab + a_base + fm * 2048 + c1);
    }
#pragma unroll
    for (int fn = 0; fn < 3; ++fn) {
      b0[fn][0] = *(const bf16x8*)(Bb + b_base + fn * 2048 + c0);
      b0[fn][1] = *(const bf16x8*)(Bb + b_base + fn * 2048 + c1);
    }
    __builtin_amdgcn_s_setprio(1);
#pragma unroll
    for (int fm = 0; fm < 2; ++fm)
#pragma unroll
      for (int fn = 0; fn < 3; ++fn)
#pragma unroll
        for (int ks = 0; ks < 2; ++ks)
          acc[0][fm][0][fn] = __builtin_amdgcn_mfma_f32_16x16x32_bf16(a[fm][ks], b0[fn][ks], acc[0][fm][0][fn], 0, 0, 0);
    __builtin_amdgcn_s_setprio(0);
    __builtin_amdgcn_s_barrier();  // all waves done reading Ah0 -> stA(t+2,0) may overwrite

    // ===== ph2 (Ah0 x Bh1): stage A(t+2,h0); read b1(6); MFMA (a held) =====
    stA(t + 2, 0);
#pragma unroll
    for (int fn = 0; fn < 3; ++fn) {
      b1[fn][0] = *(const bf16x8*)(Bb + 12288 + b_base + fn * 2048 + c0);
      b1[fn][1] = *(const bf16x8*)(Bb + 12288 + b_base + fn * 2048 + c1);
    }
    __builtin_amdgcn_s_setprio(1);
#pragma unroll
    for (int fm = 0; fm < 2; ++fm)
#pragma unroll
      for (int fn = 0; fn < 3; ++fn)
#pragma unroll
        for (int ks = 0; ks < 2; ++ks)
          acc[0][fm][1][fn] = __builtin_amdgcn_mfma_f32_16x16x32_bf16(a[fm][ks], b1[fn][ks], acc[0][fm][1][fn], 0, 0, 0);
    __builtin_amdgcn_s_setprio(0);

    // ===== ph3 (Ah1 x Bh1): read a <- Ah1(4); MFMA (b1 held) =====
#pragma unroll
    for (int fm = 0; fm < 2; ++fm) {
      a[fm][0] = *(const bf16x8*)(Ab + 16384 + a_base + fm * 2048 + c0);
      a[fm][1] = *(const bf16x8*)(Ab + 16384 + a_base + fm * 2048 + c1);
    }
    __builtin_amdgcn_s_setprio(1);
#pragma unroll
    for (int fm = 0; fm < 2; ++fm)
#pragma unroll
      for (int fn = 0; fn < 3; ++fn)
#pragma unroll
        for (int ks = 0; ks < 2; ++ks)
          acc[1][fm][1][fn] = __builtin_amdgcn_mfma_f32_16x16x32_bf16(a[fm][ks], b1[fn][ks], acc[1][fm][1][fn], 0, 0, 0);
    __builtin_amdgcn_s_setprio(0);
    __builtin_amdgcn_s_barrier();  // all waves done reading Ah1 -> stA(t+2,1) may overwrite

    // ===== ph4 (Ah1 x Bh0): stage A(t+2,h1); MFMA (a, b0 held); boundary =====
    stA(t + 2, 1);
    __builtin_amdgcn_s_setprio(1);
#pragma unroll
    for (int fm = 0; fm < 2; ++fm)
#pragma unroll
      for (int fn = 0; fn < 3; ++fn)
#pragma unroll
        for (int ks = 0; ks < 2; ++ks)
          acc[1][fm][0][fn] = __builtin_amdgcn_mfma_f32_16x16x32_bf16(a[fm][ks], b0[fn][ks], acc[1][fm][0][fn], 0, 0, 0);
    __builtin_amdgcn_s_setprio(0);
    if (t + 1 < NT) {
      if (t + 1 == NT - 1) asm volatile("s_waitcnt vmcnt(0)" ::: "memory");
      else                 asm volatile("s_waitcnt vmcnt(4)" ::: "memory");
    }
    __builtin_amdgcn_s_barrier();  // buffer swap
  }

  // ---- epilogue: bf16 C write ----
#pragma unroll
  for (int ah = 0; ah < 2; ++ah)
#pragma unroll
    for (int fm = 0; fm < 2; ++fm) {
      int row0 = m0 + ah * 128 + wm * 32 + fm * 16 + l4 * 4;
#pragma unroll
      for (int bh = 0; bh < 2; ++bh)
#pragma unroll
        for (int fn = 0; fn < 3; ++fn) {
          int col = n0 + bh * 96 + wn * 48 + fn * 16 + l15;
#pragma unroll
          for (int r = 0; r < 4; ++r)
            C[(size_t)(row0 + r) * N + col] = f2b(acc[ah][fm][bh][fn][r]);
        }
    }
}

// ===== 128 x 128 GEMM, K-SPLIT waves, per-wave 64x64 — out proj (PROVEN) =====
__global__ __launch_bounds__(512, 4) void k_gksplit(const unsigned short* __restrict__ A,
                                                    const unsigned short* __restrict__ B,
                                                    float* __restrict__ C,
                                                    int M, int N, int K) {
  extern __shared__ __align__(16) unsigned short smem[];
  char* Sc = (char*)smem;
  const int tid = threadIdx.x;
  const int wvid = tid >> 6, l = tid & 63;
  const int wm = wvid & 1, wn = (wvid >> 1) & 1, wk = wvid >> 2;
  const int l15 = l & 15, l4 = l >> 4;

  const int cpx = gridDim.x >> 3;
  const int swz = (blockIdx.x & 7) * cpx + (blockIdx.x >> 3);
  const int mtiles = M >> 7;
  const int m0 = (swz % mtiles) * 128;
  const int n0 = (swz / mtiles) * 128;

  const int NT = K >> 6;

  const int rsw = (l15 & 7) << 4;
  const int a_base = (wm * 64 + l15) * 128;
  const int b_base = (wn * 64 + l15) * 128;
  const int ck = (wk * 64 + l4 * 16) ^ rsw;

  const int srow = l >> 3;
  const int st_k8 = (l & 7) ^ (srow & 7);

  auto stA = [&](int tt) {
    if (tt >= NT) return;
    const unsigned short* g = A + (size_t)(m0 + wvid * 8 + srow) * K + tt * 64 + st_k8 * 8;
    char* lb = Sc + (tt & 1) * 16384 + wvid * 1024;
#pragma unroll
    for (int j = 0; j < 2; ++j)
      gl16(g + (size_t)(j * 64) * K, lb + j * 8192);
  };
  auto stB = [&](int tt) {
    if (tt >= NT) return;
    const unsigned short* g = B + (size_t)(n0 + wvid * 8 + srow) * K + tt * 64 + st_k8 * 8;
    char* lb = Sc + 32768 + (tt & 1) * 16384 + wvid * 1024;
#pragma unroll
    for (int j = 0; j < 2; ++j)
      gl16(g + (size_t)(j * 64) * K, lb + j * 8192);
  };

  f32x4 acc[4][4] = {};

  stA(0); stB(0); stA(1);
  if (NT > 1) asm volatile("s_waitcnt vmcnt(2)" ::: "memory");
  else        asm volatile("s_waitcnt vmcnt(0)" ::: "memory");
  __builtin_amdgcn_s_barrier();

  for (int t = 0; t < NT; ++t) {
    const char* Ab = Sc + (t & 1) * 16384;
    const char* Bb = Sc + 32768 + (t & 1) * 16384;
    stB(t + 1);
    bf16x8 a[4], b[4];
#pragma unroll
    for (int fm = 0; fm < 4; ++fm) a[fm] = *(const bf16x8*)(Ab + a_base + fm * 2048 + ck);
#pragma unroll
    for (int fn = 0; fn < 4; ++fn) b[fn] = *(const bf16x8*)(Bb + b_base + fn * 2048 + ck);
    __builtin_amdgcn_s_setprio(1);
#pragma unroll
    for (int fm = 0; fm < 4; ++fm)
#pragma unroll
      for (int fn = 0; fn < 4; ++fn)
        acc[fm][fn] = __builtin_amdgcn_mfma_f32_16x16x32_bf16(a[fm], b[fn], acc[fm][fn], 0, 0, 0);
    __builtin_amdgcn_s_setprio(0);
    __builtin_amdgcn_s_barrier();
    stA(t + 2);
    if (t + 1 < NT) {
      if (t + 1 == NT - 1) asm volatile("s_waitcnt vmcnt(0)" ::: "memory");
      else                 asm volatile("s_waitcnt vmcnt(2)" ::: "memory");
      __builtin_amdgcn_s_barrier();
    }
  }

  char* xch = Sc + (wm * 2 + wn) * 16384;
  if (wk == 1) {
#pragma unroll
    for (int fm = 0; fm < 4; ++fm)
#pragma unroll
      for (int fn = 0; fn < 4; ++fn)
        *(f32x4*)(xch + (fm * 4 + fn) * 1024 + l * 16) = acc[fm][fn];
  }
  __syncthreads();
  if (wk == 0) {
#pragma unroll
    for (int fm = 0; fm < 4; ++fm) {
      int row0 = m0 + wm * 64 + fm * 16 + l4 * 4;
#pragma unroll
      for (int fn = 0; fn < 4; ++fn) {
        f32x4 o = *(const f32x4*)(xch + (fm * 4 + fn) * 1024 + l * 16);
        int col = n0 + wn * 64 + fn * 16 + l15;
#pragma unroll
        for (int r = 0; r < 4; ++r)
          C[(size_t)(row0 + r) * N + col] = acc[fm][fn][r] + o[r];
      }
    }
  }
}

// ------------- causal GQA flash attention: i8 MFMA QK^T (K=64), bf16 PV (PROVEN) -------------
__global__ __launch_bounds__(512, 4) void k_attn(const signed char* __restrict__ q_i8,
                                                 const float* __restrict__ q_ds_t,
                                                 const signed char* __restrict__ k_i8,
                                                 const float* __restrict__ k_ds_t,
                                                 const unsigned short* __restrict__ v_t,
                                                 unsigned short* __restrict__ o_bf) {
  __shared__ __align__(16) signed char K_lds[2][8192];
  __shared__ __align__(16) unsigned short V_lds[2][8192];
  __shared__ __align__(16) unsigned short P_lds[8][1024];

  const int bid = blockIdx.x;
  const int kvh = bid & 7;
  const int qt = 63 - (bid >> 3);
  const int tid = threadIdx.x, wv = tid >> 6, l = tid & 63;
  const int l15 = l & 15, l4 = l >> 4;
  const int h = kvh * 4 + (wv & 3);
  const int rh = wv >> 2;

  auto stage = [&](int b, int kt) {
    {
      int key = tid >> 3, g = tid & 7;
      int colb = (g * 16) ^ ((key & 7) << 4);
      const signed char* src = k_i8 + ((size_t)(kt * 64 + key) * NKV + kvh) * HD + colb;
      gl16(src, &K_lds[b][tid * 16]);
    }
    const unsigned short* vB = v_t + (size_t)kvh * HD * S_LEN + (size_t)kt * 64;
#pragma unroll
    for (int j = 0; j < 2; ++j) {
      int wi = j * 8 + wv;
      int slot = wi * 64 + l;
      int d = slot >> 3;
      int ckb = ((slot & 7) * 16) ^ ((d & 7) << 4);
      gl16(vB + (size_t)d * S_LEN + (ckb >> 1), &V_lds[b][wi * 512]);
    }
  };

  const int qrow_lo = qt * 32 + rh * 16;
  const int qg = qrow_lo + l15;
  const int crow = qrow_lo + l4 * 4;

  i32x4 qf[2];
  {
    const signed char* qp = q_i8 + ((size_t)qg * NH + h) * HD + l4 * 16;
    qf[0] = *(const i32x4*)(qp);
    qf[1] = *(const i32x4*)(qp + 64);
  }
  const float qsS = ATT_SCALE_L2E * q_ds_t[(size_t)h * S_LEN + qg];

  float m_run = -3.0e38f, l_run = 0.f;
  f32x4 o_acc[8] = {};

  const int nkt = (qt >> 1) + 1;
  stage(0, 0);
  __syncthreads();

  const int psw = (l15 & 7) << 4;

  auto tileBody = [&](auto mc, int kt) {
    constexpr bool MASKED = decltype(mc)::value;
    const int cur = kt & 1;
    f32x4 ksd[4];
    {
      const f32x4* kdp = (const f32x4*)(k_ds_t + (size_t)kvh * S_LEN + kt * 64 + l4 * 4);
#pragma unroll
      for (int nt = 0; nt < 4; ++nt) ksd[nt] = kdp[nt * 4];
    }
    if (kt + 1 < nkt) stage(cur ^ 1, kt + 1);

    i32x4 sacc[4] = {};
#pragma unroll
    for (int nt = 0; nt < 4; ++nt) {
      int key = nt * 16 + l15;
#pragma unroll
      for (int kd = 0; kd < 2; ++kd) {
        int byte = key * 128 + kd * 64 + l4 * 16;
        byte ^= (key & 7) << 4;
        i32x4 kf = *(const i32x4*)(&K_lds[cur][0] + byte);
        sacc[nt] = __builtin_amdgcn_mfma_i32_16x16x64_i8(kf, qf[kd], sacc[nt], 0, 0, 0);
      }
    }

    float p[4][4];
    float tmax = -3.0e38f;
#pragma unroll
    for (int nt = 0; nt < 4; ++nt) {
#pragma unroll
      for (int r = 0; r < 4; ++r) {
        float sc = (float)sacc[nt][r] * (qsS * ksd[nt][r]);
        if constexpr (MASKED) {
          int keyg = kt * 64 + nt * 16 + l4 * 4 + r;
          sc = (keyg <= qg) ? sc : -3.0e38f;
        }
        p[nt][r] = sc;
        tmax = fmaxf(tmax, sc);
      }
    }
    tmax = fmaxf(tmax, __shfl_xor(tmax, 16));
    tmax = fmaxf(tmax, __shfl_xor(tmax, 32));

    float nm = fmaxf(m_run, tmax);
    bool need = tmax > m_run + 11.0f;
    if (__ballot(need)) {
      float corr = __builtin_amdgcn_exp2f(m_run - nm);
      m_run = nm;
      l_run *= corr;
      float cq[4];
#pragma unroll
      for (int r = 0; r < 4; ++r) cq[r] = __shfl(corr, (l & 48) | (l4 * 4 + r));
#pragma unroll
      for (int dt = 0; dt < 8; ++dt)
#pragma unroll
        for (int r = 0; r < 4; ++r) o_acc[dt][r] *= cq[r];
    }

    float psum = 0.f;
#pragma unroll
    for (int nt = 0; nt < 4; ++nt)
#pragma unroll
      for (int r = 0; r < 4; ++r) {
        float e = __builtin_amdgcn_exp2f(p[nt][r] - m_run);
        p[nt][r] = e;
        psum += e;
      }
    psum += __shfl_xor(psum, 16);
    psum += __shfl_xor(psum, 32);
    l_run += psum;

#pragma unroll
    for (int nt = 0; nt < 4; ++nt) {
      bf16x4 pk;
      pk[0] = (__bf16)p[nt][0]; pk[1] = (__bf16)p[nt][1];
      pk[2] = (__bf16)p[nt][2]; pk[3] = (__bf16)p[nt][3];
      int bw = l15 * 128 + ((nt * 32 + l4 * 8) ^ psw);
      *(bf16x4*)((char*)&P_lds[wv][0] + bw) = pk;
    }
    bf16x8 pa[2];
#pragma unroll
    for (int kc = 0; kc < 2; ++kc) {
      int br = l15 * 128 + ((kc * 64 + l4 * 16) ^ psw);
      pa[kc] = *(const bf16x8*)((const char*)&P_lds[wv][0] + br);
    }

#pragma unroll
    for (int dt = 0; dt < 8; ++dt) {
      int d = dt * 16 + l15;
      int swzv = (d & 7) << 4;
#pragma unroll
      for (int kc = 0; kc < 2; ++kc) {
        int byte = d * 128 + ((kc * 64 + l4 * 16) ^ swzv);
        bf16x8 vb = *(const bf16x8*)((const char*)&V_lds[cur][0] + byte);
        o_acc[dt] = __builtin_amdgcn_mfma_f32_16x16x32_bf16(pa[kc], vb, o_acc[dt], 0, 0, 0);
      }
    }
    __syncthreads();
  };

  for (int kt = 0; kt + 1 < nkt; ++kt) tileBody(BoolC<false>{}, kt);
  tileBody(BoolC<true>{}, nkt - 1);

  float inv = 1.0f / l_run;
  float invq[4];
#pragma unroll
  for (int r = 0; r < 4; ++r) invq[r] = __shfl(inv, (l & 48) | (l4 * 4 + r));
#pragma unroll
  for (int dt = 0; dt < 8; ++dt)
#pragma unroll
    for (int r = 0; r < 4; ++r)
      o_bf[(size_t)(crow + r) * (NH * HD) + h * HD + dt * 16 + l15] =
          f2b(o_acc[dt][r] * invq[r]);
}

extern "C" void kernel_launch(void* const* d_in, const int* in_sizes, int n_in,
                              void* d_out, int out_size, void* d_ws, size_t ws_size,
                              hipStream_t stream) {
  const float* x    = (const float*)d_in[0];
  const float* Wq   = (const float*)d_in[1];
  const float* Wk   = (const float*)d_in[2];
  const float* Wv   = (const float*)d_in[3];
  const float* Wo   = (const float*)d_in[4];
  const float* cost = (const float*)d_in[5];
  const float* sint = (const float*)d_in[6];
  float* out = (float*)d_out;
  char* ws = (char*)d_ws;

  unsigned short* xb     = (unsigned short*)(ws);                 // 16 MB (dead after gemm1)
  unsigned short* wqkv_t = (unsigned short*)(ws + 16777216);      // 48 MB (dead after gemm1)
  unsigned short* wo_t   = (unsigned short*)(ws + 67108864);      // 32 MB
  unsigned short* qkv    = (unsigned short*)(ws + 100663296);     // 24 MB bf16
  signed char*    q_i8   = (signed char*)(ws + 150994944);        // 8 MB
  signed char*    k_i8   = (signed char*)(ws + 167772160);        // 2 MB
  float*          q_ds_t = (float*)(ws + 176160768);              // 256 KB [NH][S]
  float*          k_ds_t = (float*)(ws + 176422912);              // 64 KB  [NKV][S]
  unsigned short* o_bf   = (unsigned short*)(ws + 176488448);     // 16 MB
  unsigned short* v_t    = (unsigned short*)(ws);                 // 4 MB, aliases dead xb

  hipFuncSetAttribute((const void*)k_g256x192,
                      hipFuncAttributeMaxDynamicSharedMemorySize, 114688);
  hipFuncSetAttribute((const void*)k_gksplit,
                      hipFuncAttributeMaxDynamicSharedMemorySize, 65536);

  // merged prep: cvt_x + Wq/Wk/Wv/Wo transposes in one launch
  k_prep<<<dim3(18432), 256, 0, stream>>>(x, Wq, Wk, Wv, Wo, xb, wqkv_t, wo_t);
  // QKV proj: 256x192 tiles, minimal-barrier quadrant schedule -> 256 blocks = 1/CU
  k_g256x192<<<dim3(256), 512, 114688, stream>>>(xb, wqkv_t, qkv, 2048, 6144, 4096);
  // merged post: RoPE + int8 quant (q,k bytes) + V^T transpose
  k_post<<<dim3(20992), 256, 0, stream>>>(qkv, cost, sint, q_i8, q_ds_t, k_i8, k_ds_t, v_t);
  // attention: i8 QK^T (K=64), 512 blocks x 512 threads, mask-elided tiles
  k_attn<<<dim3(512), 512, 0, stream>>>(q_i8, q_ds_t, k_i8, k_ds_t, v_t, o_bf);
  // out proj: 128x128 tiles, K-split waves -> 512 blocks = 2/CU
  k_gksplit<<<dim3(512), 512, 65536, stream>>>(o_bf, wo_t, out, 2048, 4096, 4096);
}